// Round 1
// baseline (936.699 us; speedup 1.0000x reference)
//
#include <hip/hip_runtime.h>
#include <math.h>

#define Bd 4
#define Cd 256
#define Hd 128
#define Wd 128
#define HW (Hd*Wd)

#define PX 128   // pixels per block in fused kernel
#define KC 32    // c-chunk staged in LDS

// ---------------------------------------------------------------------------
// Kernel 0: transpose w0,w1 (row-major [O][C]) -> w0T,w1T ([C][O]) so the
// fused kernel's LDS staging is a linear copy.
// ---------------------------------------------------------------------------
__global__ __launch_bounds__(256) void transpose_k(
    const float* __restrict__ w0, const float* __restrict__ w1,
    float* __restrict__ w0T, float* __restrict__ w1T) {
  __shared__ float tile[32][33];
  const float* src = blockIdx.y ? w1 : w0;
  float*       dst = blockIdx.y ? w1T : w0T;
  const int bx = blockIdx.x & 7, by = blockIdx.x >> 3;   // 8x8 grid of 32x32 tiles
  const int tx = threadIdx.x & 31, ty = threadIdx.x >> 5; // 32 x 8
#pragma unroll
  for (int i = 0; i < 32; i += 8)
    tile[ty + i][tx] = src[(by*32 + ty + i)*Cd + bx*32 + tx];
  __syncthreads();
#pragma unroll
  for (int i = 0; i < 32; i += 8)
    dst[(bx*32 + ty + i)*Cd + by*32 + tx] = tile[tx][ty + i];
}

// ---------------------------------------------------------------------------
// Kernel 1: deformable 3x3 unfold fused with max over the 9 taps.
// One thread = one pixel; bilinear weights/indices computed once, reused
// across all 256 channels. Validity folded into corner weights.
// ---------------------------------------------------------------------------
__global__ __launch_bounds__(256) void deform_max_k(
    const float* __restrict__ x, const float* __restrict__ off,
    float* __restrict__ q) {
  const int b   = blockIdx.y;
  const int hw0 = (blockIdx.x << 8) + threadIdx.x;   // 64 blocks * 256 = 16384
  const int h   = hw0 >> 7;
  const int w   = hw0 & (Wd - 1);

  const float* offb = off + ((size_t)b * 18) * HW + hw0;

  int   i00[9], i01[9], i10[9], i11[9];
  float c00[9], c01[9], c10[9], c11[9];
#pragma unroll
  for (int k = 0; k < 9; ++k) {
    const int kh = k / 3 - 1, kw = k % 3 - 1;
    const float oy = offb[(size_t)(2*k)   * HW];
    const float ox = offb[(size_t)(2*k+1) * HW];
    const float py = (float)(h + kh) + oy;
    const float px = (float)(w + kw) + ox;
    const float y0f = floorf(py), x0f = floorf(px);
    const float wy = py - y0f, wx = px - x0f;
    const int y0 = (int)y0f, x0 = (int)x0f;
    const int y1 = y0 + 1,  x1 = x0 + 1;
    const float vy0 = (y0 >= 0 && y0 < Hd) ? 1.f : 0.f;
    const float vy1 = (y1 >= 0 && y1 < Hd) ? 1.f : 0.f;
    const float vx0 = (x0 >= 0 && x0 < Wd) ? 1.f : 0.f;
    const float vx1 = (x1 >= 0 && x1 < Wd) ? 1.f : 0.f;
    const int cy0 = min(max(y0, 0), Hd-1), cy1 = min(max(y1, 0), Hd-1);
    const int cx0 = min(max(x0, 0), Wd-1), cx1 = min(max(x1, 0), Wd-1);
    i00[k] = cy0 * Wd + cx0;
    i01[k] = cy0 * Wd + cx1;
    i10[k] = cy1 * Wd + cx0;
    i11[k] = cy1 * Wd + cx1;
    c00[k] = (1.f-wy)*(1.f-wx) * vy0*vx0;
    c01[k] = (1.f-wy)*wx       * vy0*vx1;
    c10[k] = wy*(1.f-wx)       * vy1*vx0;
    c11[k] = wy*wx             * vy1*vx1;
  }

  const float* xb = x + ((size_t)b * Cd) * HW;
  float*       qb = q + ((size_t)b * Cd) * HW + hw0;
#pragma unroll 2
  for (int c = 0; c < Cd; ++c) {
    const float* xc = xb + (size_t)c * HW;
    float m = -3.402823466e38f;
#pragma unroll
    for (int k = 0; k < 9; ++k) {
      const float s = c00[k]*xc[i00[k]] + c01[k]*xc[i01[k]]
                    + c10[k]*xc[i10[k]] + c11[k]*xc[i11[k]];
      m = fmaxf(m, s);
    }
    qb[(size_t)c * HW] = m;
  }
}

// ---------------------------------------------------------------------------
// Kernel 2: fused  query = W0*q + b0, key = W1*x + b1, channel-norm both,
// out = <qn, kn>.  Block = 512 threads, tile = 256 outputs x 128 pixels.
// Thread (o_t = tid&31, px_t = tid>>5) owns o in {4*o_t..+3, 128+4*o_t..+3}
// and px in {8*px_t..+7}: wave LDS reads are contiguous (conflict-free),
// q/x reads broadcast within the 32-lane o-group.
// ---------------------------------------------------------------------------
__global__ __launch_bounds__(512) void fused_k(
    const float* __restrict__ x, const float* __restrict__ q,
    const float* __restrict__ w0T, const float* __restrict__ w1T,
    const float* __restrict__ b0, const float* __restrict__ b1,
    float* __restrict__ out) {
  __shared__ float w0s[KC * 256];   // 32 KB
  __shared__ float w1s[KC * 256];   // 32 KB
  __shared__ float qs [KC * PX];    // 16 KB
  __shared__ float xs [KC * PX];    // 16 KB

  const int b    = blockIdx.y;
  const int px0  = blockIdx.x * PX;
  const int tid  = threadIdx.x;
  const int o_t  = tid & 31;
  const int px_t = tid >> 5;

  float accQ[8][8], accK[8][8];
#pragma unroll
  for (int i = 0; i < 8; ++i) {
    const int o = (i < 4) ? (4*o_t + i) : (128 + 4*o_t + (i - 4));
    const float bq = b0[o], bk = b1[o];
#pragma unroll
    for (int j = 0; j < 8; ++j) { accQ[i][j] = bq; accK[i][j] = bk; }
  }

  const float* qb = q + ((size_t)b * Cd) * HW + px0;
  const float* xb = x + ((size_t)b * Cd) * HW + px0;

  for (int kc = 0; kc < Cd; kc += KC) {
    __syncthreads();
    // stage W chunks: 2 x 8192 floats, linear copy
    {
      const float4* s0 = (const float4*)(w0T + (size_t)kc * 256);
      const float4* s1 = (const float4*)(w1T + (size_t)kc * 256);
      float4* d0 = (float4*)w0s;
      float4* d1 = (float4*)w1s;
#pragma unroll
      for (int i = 0; i < 4; ++i) {
        d0[tid*4 + i] = s0[tid*4 + i];
        d1[tid*4 + i] = s1[tid*4 + i];
      }
      // stage q/x tiles: 2 x 4096 floats
#pragma unroll
      for (int i = 0; i < 2; ++i) {
        const int f  = tid*2 + i;       // 0..1023
        const int cc = f >> 5, p4 = f & 31;
        ((float4*)qs)[cc*(PX/4) + p4] =
            ((const float4*)(qb + (size_t)(kc+cc) * HW))[p4];
        ((float4*)xs)[cc*(PX/4) + p4] =
            ((const float4*)(xb + (size_t)(kc+cc) * HW))[p4];
      }
    }
    __syncthreads();

#pragma unroll 4
    for (int cc = 0; cc < KC; ++cc) {
      float a0[8], a1[8], qv[8], xv[8];
      *(float4*)&a0[0] = *(const float4*)&w0s[cc*256 + 4*o_t];
      *(float4*)&a0[4] = *(const float4*)&w0s[cc*256 + 128 + 4*o_t];
      *(float4*)&a1[0] = *(const float4*)&w1s[cc*256 + 4*o_t];
      *(float4*)&a1[4] = *(const float4*)&w1s[cc*256 + 128 + 4*o_t];
      *(float4*)&qv[0] = *(const float4*)&qs[cc*PX + 8*px_t];
      *(float4*)&qv[4] = *(const float4*)&qs[cc*PX + 8*px_t + 4];
      *(float4*)&xv[0] = *(const float4*)&xs[cc*PX + 8*px_t];
      *(float4*)&xv[4] = *(const float4*)&xs[cc*PX + 8*px_t + 4];
#pragma unroll
      for (int i = 0; i < 8; ++i)
#pragma unroll
        for (int j = 0; j < 8; ++j) {
          accQ[i][j] = fmaf(a0[i], qv[j], accQ[i][j]);
          accK[i][j] = fmaf(a1[i], xv[j], accK[i][j]);
        }
    }
  }

  // epilogue: per-pixel stats over all 256 outputs
  float outv[8];
#pragma unroll
  for (int j = 0; j < 8; ++j) {
    float sQ = 0.f, sK = 0.f, sQQ = 0.f, sKK = 0.f, sQK = 0.f;
#pragma unroll
    for (int i = 0; i < 8; ++i) {
      const float Qv = accQ[i][j], Kv = accK[i][j];
      sQ += Qv; sK += Kv;
      sQQ = fmaf(Qv, Qv, sQQ);
      sKK = fmaf(Kv, Kv, sKK);
      sQK = fmaf(Qv, Kv, sQK);
    }
    // butterfly over the 32 o-threads (masks <32 stay within each 32-lane group)
#pragma unroll
    for (int m = 1; m < 32; m <<= 1) {
      sQ  += __shfl_xor(sQ,  m, 64);
      sK  += __shfl_xor(sK,  m, 64);
      sQQ += __shfl_xor(sQQ, m, 64);
      sKK += __shfl_xor(sKK, m, 64);
      sQK += __shfl_xor(sQK, m, 64);
    }
    const float num = sQK - sQ*sK*(1.f/256.f);
    const float dq  = sQQ - sQ*sQ*(1.f/256.f) + 1e-5f;
    const float dk  = sKK - sK*sK*(1.f/256.f) + 1e-5f;
    outv[j] = num / sqrtf(dq * dk);
  }
  if (o_t == 0) {
    float* ob = out + (size_t)b * HW + px0 + px_t*8;
#pragma unroll
    for (int j = 0; j < 8; ++j) ob[j] = outv[j];
  }
}

// ---------------------------------------------------------------------------
extern "C" void kernel_launch(void* const* d_in, const int* in_sizes, int n_in,
                              void* d_out, int out_size, void* d_ws, size_t ws_size,
                              hipStream_t stream) {
  const float* x   = (const float*)d_in[0];
  const float* off = (const float*)d_in[1];
  const float* w0  = (const float*)d_in[2];
  const float* b0  = (const float*)d_in[3];
  const float* w1  = (const float*)d_in[4];
  const float* b1  = (const float*)d_in[5];
  float* out = (float*)d_out;

  float* w0T = (float*)d_ws;            // 65536 floats
  float* w1T = w0T + 65536;             // 65536 floats
  float* qws = w1T + 65536;             // B*C*H*W = 16777216 floats (64 MiB)

  transpose_k <<<dim3(64, 2),  256, 0, stream>>>(w0, w1, w0T, w1T);
  deform_max_k<<<dim3(64, Bd), 256, 0, stream>>>(x, off, qws);
  fused_k     <<<dim3(HW/PX, Bd), 512, 0, stream>>>(x, qws, w0T, w1T, b0, b1, out);
}

// Round 2
// 749.053 us; speedup vs baseline: 1.2505x; 1.2505x over previous
//
#include <hip/hip_runtime.h>
#include <math.h>

#define Bd 4
#define Cd 256
#define Hd 128
#define Wd 128
#define HW (Hd*Wd)

#define PX 128   // pixels per block in fused kernel
#define KC 32    // c-chunk staged in LDS

// ---------------------------------------------------------------------------
// Kernel 0: transpose w0,w1 (row-major [O][C]) -> w0T,w1T ([C][O]) so the
// fused kernel's LDS staging is a linear copy.
// ---------------------------------------------------------------------------
__global__ __launch_bounds__(256) void transpose_k(
    const float* __restrict__ w0, const float* __restrict__ w1,
    float* __restrict__ w0T, float* __restrict__ w1T) {
  __shared__ float tile[32][33];
  const float* src = blockIdx.y ? w1 : w0;
  float*       dst = blockIdx.y ? w1T : w0T;
  const int bx = blockIdx.x & 7, by = blockIdx.x >> 3;   // 8x8 grid of 32x32 tiles
  const int tx = threadIdx.x & 31, ty = threadIdx.x >> 5; // 32 x 8
#pragma unroll
  for (int i = 0; i < 32; i += 8)
    tile[ty + i][tx] = src[(by*32 + ty + i)*Cd + bx*32 + tx];
  __syncthreads();
#pragma unroll
  for (int i = 0; i < 32; i += 8)
    dst[(bx*32 + ty + i)*Cd + by*32 + tx] = tile[tx][ty + i];
}

// ---------------------------------------------------------------------------
// Kernel 1: deformable 3x3 unfold fused with max over the 9 taps.
// R1 change: split the channel loop across gridDim.z = 8 blocks (32 channels
// each). 256 -> 2048 workgroups lifts occupancy from the 12.5% grid-size cap
// (1 block/CU) to the VGPR cap (~75%), hiding gather latency.
// Bilinear coeffs recomputed per channel-group (cheap: 18 loads + ~300 VALU).
// ---------------------------------------------------------------------------
__global__ __launch_bounds__(256) void deform_max_k(
    const float* __restrict__ x, const float* __restrict__ off,
    float* __restrict__ q) {
  const int b   = blockIdx.y;
  const int c0  = blockIdx.z << 5;                   // 8 groups of 32 channels
  const int hw0 = (blockIdx.x << 8) + threadIdx.x;   // 64 blocks * 256 = 16384
  const int h   = hw0 >> 7;
  const int w   = hw0 & (Wd - 1);

  const float* offb = off + ((size_t)b * 18) * HW + hw0;

  int   i00[9], i01[9], i10[9], i11[9];
  float c00[9], c01[9], c10[9], c11[9];
#pragma unroll
  for (int k = 0; k < 9; ++k) {
    const int kh = k / 3 - 1, kw = k % 3 - 1;
    const float oy = offb[(size_t)(2*k)   * HW];
    const float ox = offb[(size_t)(2*k+1) * HW];
    const float py = (float)(h + kh) + oy;
    const float px = (float)(w + kw) + ox;
    const float y0f = floorf(py), x0f = floorf(px);
    const float wy = py - y0f, wx = px - x0f;
    const int y0 = (int)y0f, x0 = (int)x0f;
    const int y1 = y0 + 1,  x1 = x0 + 1;
    const float vy0 = (y0 >= 0 && y0 < Hd) ? 1.f : 0.f;
    const float vy1 = (y1 >= 0 && y1 < Hd) ? 1.f : 0.f;
    const float vx0 = (x0 >= 0 && x0 < Wd) ? 1.f : 0.f;
    const float vx1 = (x1 >= 0 && x1 < Wd) ? 1.f : 0.f;
    const int cy0 = min(max(y0, 0), Hd-1), cy1 = min(max(y1, 0), Hd-1);
    const int cx0 = min(max(x0, 0), Wd-1), cx1 = min(max(x1, 0), Wd-1);
    i00[k] = cy0 * Wd + cx0;
    i01[k] = cy0 * Wd + cx1;
    i10[k] = cy1 * Wd + cx0;
    i11[k] = cy1 * Wd + cx1;
    c00[k] = (1.f-wy)*(1.f-wx) * vy0*vx0;
    c01[k] = (1.f-wy)*wx       * vy0*vx1;
    c10[k] = wy*(1.f-wx)       * vy1*vx0;
    c11[k] = wy*wx             * vy1*vx1;
  }

  const float* xb = x + ((size_t)(b * Cd + c0)) * HW;
  float*       qb = q + ((size_t)(b * Cd + c0)) * HW + hw0;
#pragma unroll 4
  for (int c = 0; c < 32; ++c) {
    const float* xc = xb + (size_t)c * HW;
    float m = -3.402823466e38f;
#pragma unroll
    for (int k = 0; k < 9; ++k) {
      const float s = c00[k]*xc[i00[k]] + c01[k]*xc[i01[k]]
                    + c10[k]*xc[i10[k]] + c11[k]*xc[i11[k]];
      m = fmaxf(m, s);
    }
    qb[(size_t)c * HW] = m;
  }
}

// ---------------------------------------------------------------------------
// Kernel 2: fused  query = W0*q + b0, key = W1*x + b1, channel-norm both,
// out = <qn, kn>.  Block = 512 threads, tile = 256 outputs x 128 pixels.
// Thread (o_t = tid&31, px_t = tid>>5) owns o in {4*o_t..+3, 128+4*o_t..+3}
// and px in {8*px_t..+7}: wave LDS reads are contiguous (conflict-free),
// q/x reads broadcast within the 32-lane o-group.
// ---------------------------------------------------------------------------
__global__ __launch_bounds__(512) void fused_k(
    const float* __restrict__ x, const float* __restrict__ q,
    const float* __restrict__ w0T, const float* __restrict__ w1T,
    const float* __restrict__ b0, const float* __restrict__ b1,
    float* __restrict__ out) {
  __shared__ float w0s[KC * 256];   // 32 KB
  __shared__ float w1s[KC * 256];   // 32 KB
  __shared__ float qs [KC * PX];    // 16 KB
  __shared__ float xs [KC * PX];    // 16 KB

  const int b    = blockIdx.y;
  const int px0  = blockIdx.x * PX;
  const int tid  = threadIdx.x;
  const int o_t  = tid & 31;
  const int px_t = tid >> 5;

  float accQ[8][8], accK[8][8];
#pragma unroll
  for (int i = 0; i < 8; ++i) {
    const int o = (i < 4) ? (4*o_t + i) : (128 + 4*o_t + (i - 4));
    const float bq = b0[o], bk = b1[o];
#pragma unroll
    for (int j = 0; j < 8; ++j) { accQ[i][j] = bq; accK[i][j] = bk; }
  }

  const float* qb = q + ((size_t)b * Cd) * HW + px0;
  const float* xb = x + ((size_t)b * Cd) * HW + px0;

  for (int kc = 0; kc < Cd; kc += KC) {
    __syncthreads();
    // stage W chunks: 2 x 8192 floats, linear copy
    {
      const float4* s0 = (const float4*)(w0T + (size_t)kc * 256);
      const float4* s1 = (const float4*)(w1T + (size_t)kc * 256);
      float4* d0 = (float4*)w0s;
      float4* d1 = (float4*)w1s;
#pragma unroll
      for (int i = 0; i < 4; ++i) {
        d0[tid*4 + i] = s0[tid*4 + i];
        d1[tid*4 + i] = s1[tid*4 + i];
      }
      // stage q/x tiles: 2 x 4096 floats
#pragma unroll
      for (int i = 0; i < 2; ++i) {
        const int f  = tid*2 + i;       // 0..1023
        const int cc = f >> 5, p4 = f & 31;
        ((float4*)qs)[cc*(PX/4) + p4] =
            ((const float4*)(qb + (size_t)(kc+cc) * HW))[p4];
        ((float4*)xs)[cc*(PX/4) + p4] =
            ((const float4*)(xb + (size_t)(kc+cc) * HW))[p4];
      }
    }
    __syncthreads();

#pragma unroll 4
    for (int cc = 0; cc < KC; ++cc) {
      float a0[8], a1[8], qv[8], xv[8];
      *(float4*)&a0[0] = *(const float4*)&w0s[cc*256 + 4*o_t];
      *(float4*)&a0[4] = *(const float4*)&w0s[cc*256 + 128 + 4*o_t];
      *(float4*)&a1[0] = *(const float4*)&w1s[cc*256 + 4*o_t];
      *(float4*)&a1[4] = *(const float4*)&w1s[cc*256 + 128 + 4*o_t];
      *(float4*)&qv[0] = *(const float4*)&qs[cc*PX + 8*px_t];
      *(float4*)&qv[4] = *(const float4*)&qs[cc*PX + 8*px_t + 4];
      *(float4*)&xv[0] = *(const float4*)&xs[cc*PX + 8*px_t];
      *(float4*)&xv[4] = *(const float4*)&xs[cc*PX + 8*px_t + 4];
#pragma unroll
      for (int i = 0; i < 8; ++i)
#pragma unroll
        for (int j = 0; j < 8; ++j) {
          accQ[i][j] = fmaf(a0[i], qv[j], accQ[i][j]);
          accK[i][j] = fmaf(a1[i], xv[j], accK[i][j]);
        }
    }
  }

  // epilogue: per-pixel stats over all 256 outputs
  float outv[8];
#pragma unroll
  for (int j = 0; j < 8; ++j) {
    float sQ = 0.f, sK = 0.f, sQQ = 0.f, sKK = 0.f, sQK = 0.f;
#pragma unroll
    for (int i = 0; i < 8; ++i) {
      const float Qv = accQ[i][j], Kv = accK[i][j];
      sQ += Qv; sK += Kv;
      sQQ = fmaf(Qv, Qv, sQQ);
      sKK = fmaf(Kv, Kv, sKK);
      sQK = fmaf(Qv, Kv, sQK);
    }
    // butterfly over the 32 o-threads (masks <32 stay within each 32-lane group)
#pragma unroll
    for (int m = 1; m < 32; m <<= 1) {
      sQ  += __shfl_xor(sQ,  m, 64);
      sK  += __shfl_xor(sK,  m, 64);
      sQQ += __shfl_xor(sQQ, m, 64);
      sKK += __shfl_xor(sKK, m, 64);
      sQK += __shfl_xor(sQK, m, 64);
    }
    const float num = sQK - sQ*sK*(1.f/256.f);
    const float dq  = sQQ - sQ*sQ*(1.f/256.f) + 1e-5f;
    const float dk  = sKK - sK*sK*(1.f/256.f) + 1e-5f;
    outv[j] = num / sqrtf(dq * dk);
  }
  if (o_t == 0) {
    float* ob = out + (size_t)b * HW + px0 + px_t*8;
#pragma unroll
    for (int j = 0; j < 8; ++j) ob[j] = outv[j];
  }
}

// ---------------------------------------------------------------------------
extern "C" void kernel_launch(void* const* d_in, const int* in_sizes, int n_in,
                              void* d_out, int out_size, void* d_ws, size_t ws_size,
                              hipStream_t stream) {
  const float* x   = (const float*)d_in[0];
  const float* off = (const float*)d_in[1];
  const float* w0  = (const float*)d_in[2];
  const float* b0  = (const float*)d_in[3];
  const float* w1  = (const float*)d_in[4];
  const float* b1  = (const float*)d_in[5];
  float* out = (float*)d_out;

  float* w0T = (float*)d_ws;            // 65536 floats
  float* w1T = w0T + 65536;             // 65536 floats
  float* qws = w1T + 65536;             // B*C*H*W = 16777216 floats (64 MiB)

  transpose_k <<<dim3(64, 2),   256, 0, stream>>>(w0, w1, w0T, w1T);
  deform_max_k<<<dim3(64, Bd, 8), 256, 0, stream>>>(x, off, qws);
  fused_k     <<<dim3(HW/PX, Bd), 512, 0, stream>>>(x, qws, w0T, w1T, b0, b1, out);
}

// Round 3
// 520.834 us; speedup vs baseline: 1.7985x; 1.4382x over previous
//
#include <hip/hip_runtime.h>
#include <math.h>
#include <float.h>

#define Bd 4
#define Cd 256
#define Hd 128
#define Wd 128
#define HW (Hd*Wd)

#define PX 128   // pixels per block in fused kernel
#define KC 32    // c-chunk staged in LDS
#define PXP 132  // padded LDS stride for transposed q staging (132%32=4 -> <=2-way)
#define PPW 8    // pixels per wave in deform_coal_k

// ---------------------------------------------------------------------------
// Kernel 0: transpose w0,w1 (row-major [O][C]) -> w0T,w1T ([C][O]).
// ---------------------------------------------------------------------------
__global__ __launch_bounds__(256) void transpose_k(
    const float* __restrict__ w0, const float* __restrict__ w1,
    float* __restrict__ w0T, float* __restrict__ w1T) {
  __shared__ float tile[32][33];
  const float* src = blockIdx.y ? w1 : w0;
  float*       dst = blockIdx.y ? w1T : w0T;
  const int bx = blockIdx.x & 7, by = blockIdx.x >> 3;
  const int tx = threadIdx.x & 31, ty = threadIdx.x >> 5;
#pragma unroll
  for (int i = 0; i < 32; i += 8)
    tile[ty + i][tx] = src[(by*32 + ty + i)*Cd + bx*32 + tx];
  __syncthreads();
#pragma unroll
  for (int i = 0; i < 32; i += 8)
    dst[(bx*32 + ty + i)*Cd + by*32 + tx] = tile[tx][ty + i];
}

// ---------------------------------------------------------------------------
// Kernel 0b: transpose x [B][C][HW] -> xT [B][HW][C] so deform gathers are
// contiguous per (pixel,corner): 256 channels = 1KB coalesced.
// ---------------------------------------------------------------------------
__global__ __launch_bounds__(256) void transpose_x_k(
    const float* __restrict__ x, float* __restrict__ xT) {
  __shared__ float t[32][33];
  const int b   = blockIdx.z;
  const int hw0 = blockIdx.x * 32;
  const int c0  = blockIdx.y * 32;
  const int tx = threadIdx.x & 31, ty = threadIdx.x >> 5;
  const float* xb  = x  + (size_t)b * Cd * HW;
  float*       xTb = xT + (size_t)b * HW * Cd;
#pragma unroll
  for (int i = 0; i < 32; i += 8)
    t[ty + i][tx] = xb[(size_t)(c0 + ty + i) * HW + hw0 + tx];
  __syncthreads();
#pragma unroll
  for (int i = 0; i < 32; i += 8)
    xTb[(size_t)(hw0 + ty + i) * Cd + c0 + tx] = t[tx][ty + i];
}

// ---------------------------------------------------------------------------
// Kernel 1 (fast path): deformable 3x3 unfold + max, channel-coalesced.
// Wave = 1 pixel at a time; lane l owns channels 4l..4l+3 (float4).
// Bilinear coeffs are wave-uniform (computed once per pixel); every corner
// load is a contiguous 1KB wave read from xT; output is one 1KB store to qT.
// ---------------------------------------------------------------------------
__global__ __launch_bounds__(256) void deform_coal_k(
    const float* __restrict__ xT, const float* __restrict__ off,
    float* __restrict__ qT) {
  const int b     = blockIdx.y;
  const int wv    = threadIdx.x >> 6;
  const int lane  = threadIdx.x & 63;
  const int pbase = (blockIdx.x * 4 + wv) * PPW;

  const float* xTb  = xT + (size_t)b * HW * Cd + lane * 4;
  float*       qTb  = qT + (size_t)b * HW * Cd + lane * 4;
  const float* offb = off + (size_t)b * 18 * HW;

#pragma unroll 2
  for (int pi = 0; pi < PPW; ++pi) {
    const int p = pbase + pi;
    const int h = p >> 7, w = p & (Wd - 1);
    float m0 = -FLT_MAX, m1 = -FLT_MAX, m2 = -FLT_MAX, m3 = -FLT_MAX;
#pragma unroll
    for (int k = 0; k < 9; ++k) {
      const float oy = offb[(2*k)   * HW + p];
      const float ox = offb[(2*k+1) * HW + p];
      const float py = (float)(h + k/3 - 1) + oy;
      const float px = (float)(w + k%3 - 1) + ox;
      const float y0f = floorf(py), x0f = floorf(px);
      const float wy = py - y0f, wx = px - x0f;
      const int y0 = (int)y0f, x0 = (int)x0f;
      const int y1 = y0 + 1,  x1 = x0 + 1;
      const float vy0 = (y0 >= 0 && y0 < Hd) ? 1.f : 0.f;
      const float vy1 = (y1 >= 0 && y1 < Hd) ? 1.f : 0.f;
      const float vx0 = (x0 >= 0 && x0 < Wd) ? 1.f : 0.f;
      const float vx1 = (x1 >= 0 && x1 < Wd) ? 1.f : 0.f;
      const int cy0 = min(max(y0, 0), Hd-1), cy1 = min(max(y1, 0), Hd-1);
      const int cx0 = min(max(x0, 0), Wd-1), cx1 = min(max(x1, 0), Wd-1);
      const float c00 = (1.f-wy)*(1.f-wx) * vy0*vx0;
      const float c01 = (1.f-wy)*wx       * vy0*vx1;
      const float c10 = wy*(1.f-wx)       * vy1*vx0;
      const float c11 = wy*wx             * vy1*vx1;
      const size_t i00 = (size_t)(cy0 * Wd + cx0) * Cd;
      const size_t i01 = (size_t)(cy0 * Wd + cx1) * Cd;
      const size_t i10 = (size_t)(cy1 * Wd + cx0) * Cd;
      const size_t i11 = (size_t)(cy1 * Wd + cx1) * Cd;
      const float4 v00 = *(const float4*)(xTb + i00);
      const float4 v01 = *(const float4*)(xTb + i01);
      const float4 v10 = *(const float4*)(xTb + i10);
      const float4 v11 = *(const float4*)(xTb + i11);
      m0 = fmaxf(m0, fmaf(c00, v00.x, fmaf(c01, v01.x, fmaf(c10, v10.x, c11*v11.x))));
      m1 = fmaxf(m1, fmaf(c00, v00.y, fmaf(c01, v01.y, fmaf(c10, v10.y, c11*v11.y))));
      m2 = fmaxf(m2, fmaf(c00, v00.z, fmaf(c01, v01.z, fmaf(c10, v10.z, c11*v11.z))));
      m3 = fmaxf(m3, fmaf(c00, v00.w, fmaf(c01, v01.w, fmaf(c10, v10.w, c11*v11.w))));
    }
    float4 r; r.x = m0; r.y = m1; r.z = m2; r.w = m3;
    *(float4*)(qTb + (size_t)p * Cd) = r;
  }
}

// ---------------------------------------------------------------------------
// Kernel 1 (fallback path, R1 version): used only if ws_size is too small
// for the transposed buffers.
// ---------------------------------------------------------------------------
__global__ __launch_bounds__(256) void deform_max_k(
    const float* __restrict__ x, const float* __restrict__ off,
    float* __restrict__ q) {
  const int b   = blockIdx.y;
  const int c0  = blockIdx.z << 5;
  const int hw0 = (blockIdx.x << 8) + threadIdx.x;
  const int h   = hw0 >> 7;
  const int w   = hw0 & (Wd - 1);

  const float* offb = off + ((size_t)b * 18) * HW + hw0;

  int   i00[9], i01[9], i10[9], i11[9];
  float c00[9], c01[9], c10[9], c11[9];
#pragma unroll
  for (int k = 0; k < 9; ++k) {
    const int kh = k / 3 - 1, kw = k % 3 - 1;
    const float oy = offb[(size_t)(2*k)   * HW];
    const float ox = offb[(size_t)(2*k+1) * HW];
    const float py = (float)(h + kh) + oy;
    const float px = (float)(w + kw) + ox;
    const float y0f = floorf(py), x0f = floorf(px);
    const float wy = py - y0f, wx = px - x0f;
    const int y0 = (int)y0f, x0 = (int)x0f;
    const int y1 = y0 + 1,  x1 = x0 + 1;
    const float vy0 = (y0 >= 0 && y0 < Hd) ? 1.f : 0.f;
    const float vy1 = (y1 >= 0 && y1 < Hd) ? 1.f : 0.f;
    const float vx0 = (x0 >= 0 && x0 < Wd) ? 1.f : 0.f;
    const float vx1 = (x1 >= 0 && x1 < Wd) ? 1.f : 0.f;
    const int cy0 = min(max(y0, 0), Hd-1), cy1 = min(max(y1, 0), Hd-1);
    const int cx0 = min(max(x0, 0), Wd-1), cx1 = min(max(x1, 0), Wd-1);
    i00[k] = cy0 * Wd + cx0;
    i01[k] = cy0 * Wd + cx1;
    i10[k] = cy1 * Wd + cx0;
    i11[k] = cy1 * Wd + cx1;
    c00[k] = (1.f-wy)*(1.f-wx) * vy0*vx0;
    c01[k] = (1.f-wy)*wx       * vy0*vx1;
    c10[k] = wy*(1.f-wx)       * vy1*vx0;
    c11[k] = wy*wx             * vy1*vx1;
  }

  const float* xb = x + ((size_t)(b * Cd + c0)) * HW;
  float*       qb = q + ((size_t)(b * Cd + c0)) * HW + hw0;
#pragma unroll 4
  for (int c = 0; c < 32; ++c) {
    const float* xc = xb + (size_t)c * HW;
    float m = -3.402823466e38f;
#pragma unroll
    for (int k = 0; k < 9; ++k) {
      const float s = c00[k]*xc[i00[k]] + c01[k]*xc[i01[k]]
                    + c10[k]*xc[i10[k]] + c11[k]*xc[i11[k]];
      m = fmaxf(m, s);
    }
    qb[(size_t)c * HW] = m;
  }
}

// ---------------------------------------------------------------------------
// Kernel 2: fused  query = W0*q + b0, key = W1*x + b1, channel-norm both,
// out = <qn, kn>.  Template QT: q layout is [HW][C] (fast path) vs [C][HW].
// ---------------------------------------------------------------------------
template <bool QT>
__global__ __launch_bounds__(512) void fused_k(
    const float* __restrict__ x, const float* __restrict__ q,
    const float* __restrict__ w0T, const float* __restrict__ w1T,
    const float* __restrict__ b0, const float* __restrict__ b1,
    float* __restrict__ out) {
  __shared__ float w0s[KC * 256];
  __shared__ float w1s[KC * 256];
  __shared__ float qs [KC * PXP];   // padded stride when QT
  __shared__ float xs [KC * PX];

  constexpr int QSTR = QT ? PXP : PX;

  const int b    = blockIdx.y;
  const int px0  = blockIdx.x * PX;
  const int tid  = threadIdx.x;
  const int o_t  = tid & 31;
  const int px_t = tid >> 5;

  float accQ[8][8], accK[8][8];
#pragma unroll
  for (int i = 0; i < 8; ++i) {
    const int o = (i < 4) ? (4*o_t + i) : (128 + 4*o_t + (i - 4));
    const float bq = b0[o], bk = b1[o];
#pragma unroll
    for (int j = 0; j < 8; ++j) { accQ[i][j] = bq; accK[i][j] = bk; }
  }

  const float* xb = x + ((size_t)b * Cd) * HW + px0;

  for (int kc = 0; kc < Cd; kc += KC) {
    __syncthreads();
    {
      const float4* s0 = (const float4*)(w0T + (size_t)kc * 256);
      const float4* s1 = (const float4*)(w1T + (size_t)kc * 256);
      float4* d0 = (float4*)w0s;
      float4* d1 = (float4*)w1s;
#pragma unroll
      for (int i = 0; i < 4; ++i) {
        d0[tid*4 + i] = s0[tid*4 + i];
        d1[tid*4 + i] = s1[tid*4 + i];
      }
      if (QT) {
        // q is [B][HW][C]: read float4 along C, scatter-transpose into LDS.
        // Write banks: (cc*PXP + p) % 32 -> max 2-way (free).
        const float* qTb = q + ((size_t)b * HW + px0) * Cd + kc;
        const int p = tid >> 2, c4 = tid & 3;
#pragma unroll
        for (int pass = 0; pass < 2; ++pass) {
          const float4 v = *(const float4*)(qTb + (size_t)p * Cd + pass*16 + c4*4);
          const int cc = pass*16 + c4*4;
          qs[(cc+0)*PXP + p] = v.x;
          qs[(cc+1)*PXP + p] = v.y;
          qs[(cc+2)*PXP + p] = v.z;
          qs[(cc+3)*PXP + p] = v.w;
        }
      } else {
        const float* qb = q + ((size_t)b * Cd) * HW + px0;
#pragma unroll
        for (int i = 0; i < 2; ++i) {
          const int f  = tid*2 + i;
          const int cc = f >> 5, p4 = f & 31;
          ((float4*)qs)[cc*(PX/4) + p4] =
              ((const float4*)(qb + (size_t)(kc+cc) * HW))[p4];
        }
      }
#pragma unroll
      for (int i = 0; i < 2; ++i) {
        const int f  = tid*2 + i;
        const int cc = f >> 5, p4 = f & 31;
        ((float4*)xs)[cc*(PX/4) + p4] =
            ((const float4*)(xb + (size_t)(kc+cc) * HW))[p4];
      }
    }
    __syncthreads();

#pragma unroll 4
    for (int cc = 0; cc < KC; ++cc) {
      float a0[8], a1[8], qv[8], xv[8];
      *(float4*)&a0[0] = *(const float4*)&w0s[cc*256 + 4*o_t];
      *(float4*)&a0[4] = *(const float4*)&w0s[cc*256 + 128 + 4*o_t];
      *(float4*)&a1[0] = *(const float4*)&w1s[cc*256 + 4*o_t];
      *(float4*)&a1[4] = *(const float4*)&w1s[cc*256 + 128 + 4*o_t];
      *(float4*)&qv[0] = *(const float4*)&qs[cc*QSTR + 8*px_t];
      *(float4*)&qv[4] = *(const float4*)&qs[cc*QSTR + 8*px_t + 4];
      *(float4*)&xv[0] = *(const float4*)&xs[cc*PX + 8*px_t];
      *(float4*)&xv[4] = *(const float4*)&xs[cc*PX + 8*px_t + 4];
#pragma unroll
      for (int i = 0; i < 8; ++i)
#pragma unroll
        for (int j = 0; j < 8; ++j) {
          accQ[i][j] = fmaf(a0[i], qv[j], accQ[i][j]);
          accK[i][j] = fmaf(a1[i], xv[j], accK[i][j]);
        }
    }
  }

  float outv[8];
#pragma unroll
  for (int j = 0; j < 8; ++j) {
    float sQ = 0.f, sK = 0.f, sQQ = 0.f, sKK = 0.f, sQK = 0.f;
#pragma unroll
    for (int i = 0; i < 8; ++i) {
      const float Qv = accQ[i][j], Kv = accK[i][j];
      sQ += Qv; sK += Kv;
      sQQ = fmaf(Qv, Qv, sQQ);
      sKK = fmaf(Kv, Kv, sKK);
      sQK = fmaf(Qv, Kv, sQK);
    }
#pragma unroll
    for (int m = 1; m < 32; m <<= 1) {
      sQ  += __shfl_xor(sQ,  m, 64);
      sK  += __shfl_xor(sK,  m, 64);
      sQQ += __shfl_xor(sQQ, m, 64);
      sKK += __shfl_xor(sKK, m, 64);
      sQK += __shfl_xor(sQK, m, 64);
    }
    const float num = sQK - sQ*sK*(1.f/256.f);
    const float dq  = sQQ - sQ*sQ*(1.f/256.f) + 1e-5f;
    const float dk  = sKK - sK*sK*(1.f/256.f) + 1e-5f;
    outv[j] = num / sqrtf(dq * dk);
  }
  if (o_t == 0) {
    float* ob = out + (size_t)b * HW + px0 + px_t*8;
#pragma unroll
    for (int j = 0; j < 8; ++j) ob[j] = outv[j];
  }
}

// ---------------------------------------------------------------------------
extern "C" void kernel_launch(void* const* d_in, const int* in_sizes, int n_in,
                              void* d_out, int out_size, void* d_ws, size_t ws_size,
                              hipStream_t stream) {
  const float* x   = (const float*)d_in[0];
  const float* off = (const float*)d_in[1];
  const float* w0  = (const float*)d_in[2];
  const float* b0  = (const float*)d_in[3];
  const float* w1  = (const float*)d_in[4];
  const float* b1  = (const float*)d_in[5];
  float* out = (float*)d_out;

  float* w0T = (float*)d_ws;                 // 65536 floats
  float* w1T = w0T + 65536;                  // 65536 floats
  float* buf = w1T + 65536;

  const size_t need_fast = ((size_t)2*65536 + (size_t)2*Bd*Cd*HW) * 4;
  const bool fast = ws_size >= need_fast;

  transpose_k<<<dim3(64, 2), 256, 0, stream>>>(w0, w1, w0T, w1T);

  if (fast) {
    float* xT = buf;                         // [B][HW][C], 64 MiB
    float* qT = xT + (size_t)Bd*Cd*HW;       // [B][HW][C], 64 MiB
    transpose_x_k<<<dim3(HW/32, Cd/32, Bd), 256, 0, stream>>>(x, xT);
    deform_coal_k<<<dim3(HW/(4*PPW), Bd), 256, 0, stream>>>(xT, off, qT);
    fused_k<true><<<dim3(HW/PX, Bd), 512, 0, stream>>>(x, qT, w0T, w1T, b0, b1, out);
  } else {
    float* qws = buf;                        // [B][C][HW], 64 MiB
    deform_max_k<<<dim3(64, Bd, 8), 256, 0, stream>>>(x, off, qws);
    fused_k<false><<<dim3(HW/PX, Bd), 512, 0, stream>>>(x, qws, w0T, w1T, b0, b1, out);
  }
}

// Round 4
// 372.245 us; speedup vs baseline: 2.5163x; 1.3992x over previous
//
#include <hip/hip_runtime.h>
#include <math.h>
#include <float.h>

#define Bd 4
#define Cd 256
#define Hd 128
#define Wd 128
#define HW (Hd*Wd)

#define PX 128   // pixels per block in fallback fused kernel
#define KC 32
#define PXP 132
#define PPW 8    // pixels per wave in deform_coal_k

#define PXT 64   // pixels per block in MFMA fused kernel
#define CSTR 264 // padded LDS row stride (bf16 elems); 528 B -> conflict-free b128

typedef __attribute__((ext_vector_type(8))) short s16x8;
typedef __attribute__((ext_vector_type(4))) float f32x4;

// rne float -> bf16 hi, and bf16(residual) lo
__device__ __forceinline__ void bf16split(float v, ushort& h, ushort& lo_) {
  uint u = __builtin_bit_cast(uint, v);
  uint uh = u + 0x7FFFu + ((u >> 16) & 1u);
  ushort hh = (ushort)(uh >> 16);
  float hf = __builtin_bit_cast(float, (uint)hh << 16);
  float res = v - hf;                       // exact
  uint r = __builtin_bit_cast(uint, res);
  uint rl = r + 0x7FFFu + ((r >> 16) & 1u);
  h = hh; lo_ = (ushort)(rl >> 16);
}

// ---------------------------------------------------------------------------
// prep_w_k: pack w0,w1 ([O][C] fp32) into MFMA-A-fragment order, hi/lo bf16.
// Layout: wpk[((mat*2+part)*8 + kc)*16 + tile][lane][8]
//   element j = W[tile*16 + (lane&15)][kc*32 + (lane>>4)*8 + j]
// ---------------------------------------------------------------------------
__global__ __launch_bounds__(256) void prep_w_k(
    const float* __restrict__ w0, const float* __restrict__ w1,
    ushort* __restrict__ wpk) {
  const int t    = blockIdx.x * 256 + threadIdx.x;  // 0..16383
  const int lane = t & 63;
  const int tile = (t >> 6) & 15;
  const int kc   = (t >> 10) & 7;
  const int mat  = t >> 13;
  const float* wsrc = mat ? w1 : w0;
  const int o  = tile * 16 + (lane & 15);
  const int c0 = kc * 32 + (lane >> 4) * 8;
  ushort hi[8], lo[8];
#pragma unroll
  for (int j = 0; j < 8; ++j)
    bf16split(wsrc[o * Cd + c0 + j], hi[j], lo[j]);
  const size_t bh = ((((size_t)(mat * 2 + 0) * 8 + kc) * 16 + tile) * 64 + lane) * 8;
  const size_t bl = ((((size_t)(mat * 2 + 1) * 8 + kc) * 16 + tile) * 64 + lane) * 8;
#pragma unroll
  for (int j = 0; j < 8; ++j) { wpk[bh + j] = hi[j]; wpk[bl + j] = lo[j]; }
}

// ---------------------------------------------------------------------------
// transpose_x_k: x [B][C][HW] -> xT [B][HW][C] (fp32), for coalesced gathers.
// ---------------------------------------------------------------------------
__global__ __launch_bounds__(256) void transpose_x_k(
    const float* __restrict__ x, float* __restrict__ xT) {
  __shared__ float t[32][33];
  const int b   = blockIdx.z;
  const int hw0 = blockIdx.x * 32;
  const int c0  = blockIdx.y * 32;
  const int tx = threadIdx.x & 31, ty = threadIdx.x >> 5;
  const float* xb  = x  + (size_t)b * Cd * HW;
  float*       xTb = xT + (size_t)b * HW * Cd;
#pragma unroll
  for (int i = 0; i < 32; i += 8)
    t[ty + i][tx] = xb[(size_t)(c0 + ty + i) * HW + hw0 + tx];
  __syncthreads();
#pragma unroll
  for (int i = 0; i < 32; i += 8)
    xTb[(size_t)(hw0 + ty + i) * Cd + c0 + tx] = t[tx][ty + i];
}

// ---------------------------------------------------------------------------
// deform_coal_k: deformable 3x3 unfold + max, channel-coalesced (fp32).
// ---------------------------------------------------------------------------
__global__ __launch_bounds__(256) void deform_coal_k(
    const float* __restrict__ xT, const float* __restrict__ off,
    float* __restrict__ qT) {
  const int b     = blockIdx.y;
  const int wv    = threadIdx.x >> 6;
  const int lane  = threadIdx.x & 63;
  const int pbase = (blockIdx.x * 4 + wv) * PPW;

  const float* xTb  = xT + (size_t)b * HW * Cd + lane * 4;
  float*       qTb  = qT + (size_t)b * HW * Cd + lane * 4;
  const float* offb = off + (size_t)b * 18 * HW;

#pragma unroll 2
  for (int pi = 0; pi < PPW; ++pi) {
    const int p = pbase + pi;
    const int h = p >> 7, w = p & (Wd - 1);
    float m0 = -FLT_MAX, m1 = -FLT_MAX, m2 = -FLT_MAX, m3 = -FLT_MAX;
#pragma unroll
    for (int k = 0; k < 9; ++k) {
      const float oy = offb[(2*k)   * HW + p];
      const float ox = offb[(2*k+1) * HW + p];
      const float py = (float)(h + k/3 - 1) + oy;
      const float px = (float)(w + k%3 - 1) + ox;
      const float y0f = floorf(py), x0f = floorf(px);
      const float wy = py - y0f, wx = px - x0f;
      const int y0 = (int)y0f, x0 = (int)x0f;
      const int y1 = y0 + 1,  x1 = x0 + 1;
      const float vy0 = (y0 >= 0 && y0 < Hd) ? 1.f : 0.f;
      const float vy1 = (y1 >= 0 && y1 < Hd) ? 1.f : 0.f;
      const float vx0 = (x0 >= 0 && x0 < Wd) ? 1.f : 0.f;
      const float vx1 = (x1 >= 0 && x1 < Wd) ? 1.f : 0.f;
      const int cy0 = min(max(y0, 0), Hd-1), cy1 = min(max(y1, 0), Hd-1);
      const int cx0 = min(max(x0, 0), Wd-1), cx1 = min(max(x1, 0), Wd-1);
      const float c00 = (1.f-wy)*(1.f-wx) * vy0*vx0;
      const float c01 = (1.f-wy)*wx       * vy0*vx1;
      const float c10 = wy*(1.f-wx)       * vy1*vx0;
      const float c11 = wy*wx             * vy1*vx1;
      const size_t i00 = (size_t)(cy0 * Wd + cx0) * Cd;
      const size_t i01 = (size_t)(cy0 * Wd + cx1) * Cd;
      const size_t i10 = (size_t)(cy1 * Wd + cx0) * Cd;
      const size_t i11 = (size_t)(cy1 * Wd + cx1) * Cd;
      const float4 v00 = *(const float4*)(xTb + i00);
      const float4 v01 = *(const float4*)(xTb + i01);
      const float4 v10 = *(const float4*)(xTb + i10);
      const float4 v11 = *(const float4*)(xTb + i11);
      m0 = fmaxf(m0, fmaf(c00, v00.x, fmaf(c01, v01.x, fmaf(c10, v10.x, c11*v11.x))));
      m1 = fmaxf(m1, fmaf(c00, v00.y, fmaf(c01, v01.y, fmaf(c10, v10.y, c11*v11.y))));
      m2 = fmaxf(m2, fmaf(c00, v00.z, fmaf(c01, v01.z, fmaf(c10, v10.z, c11*v11.z))));
      m3 = fmaxf(m3, fmaf(c00, v00.w, fmaf(c01, v01.w, fmaf(c10, v10.w, c11*v11.w))));
    }
    float4 r; r.x = m0; r.y = m1; r.z = m2; r.w = m3;
    *(float4*)(qTb + (size_t)p * Cd) = r;
  }
}

// ---------------------------------------------------------------------------
// fused_mfma_k: Q = W0*q + b0, K = W1*x + b1 via split-bf16 MFMA
// (3 passes: AhBh + AhBl + AlBh), channel-norm cosine epilogue.
// Block = 512 thr = 8 waves; tile = 256 outs x 64 px; wave w owns outs
// [32w, 32w+32). Activations staged once (fp32 -> hi/lo bf16 LDS), so the
// K-loop has NO barriers. Weights read as A-fragments directly from the
// L2-resident pack (1 KB coalesced per frag).
// ---------------------------------------------------------------------------
__global__ __launch_bounds__(512) void fused_mfma_k(
    const float* __restrict__ xT, const float* __restrict__ qT,
    const ushort* __restrict__ wpk,
    const float* __restrict__ b0, const float* __restrict__ b1,
    float* __restrict__ out) {
  __shared__ ushort act[4 * PXT * CSTR];   // qh | ql | xh | xl = 135168 B
  const int b   = blockIdx.y;
  const int px0 = blockIdx.x * PXT;
  const int tid = threadIdx.x;
  const int l   = tid & 63, wv = tid >> 6;

  // ---- stage activations: fp32 -> hi/lo bf16 in LDS
  {
    const int r  = tid >> 3;          // 0..63
    const int c0 = (tid & 7) * 32;    // 0..224
    const float* qrow = qT + ((size_t)b * HW + px0 + r) * Cd + c0;
    const float* xrow = xT + ((size_t)b * HW + px0 + r) * Cd + c0;
    ushort* dq_h = act + 0 * PXT * CSTR + r * CSTR + c0;
    ushort* dq_l = act + 1 * PXT * CSTR + r * CSTR + c0;
    ushort* dx_h = act + 2 * PXT * CSTR + r * CSTR + c0;
    ushort* dx_l = act + 3 * PXT * CSTR + r * CSTR + c0;
#pragma unroll
    for (int i = 0; i < 8; ++i) {
      const float4 qv = ((const float4*)qrow)[i];
      const float4 xv = ((const float4*)xrow)[i];
      ushort4 qh, ql, xh, xl;
      bf16split(qv.x, qh.x, ql.x); bf16split(qv.y, qh.y, ql.y);
      bf16split(qv.z, qh.z, ql.z); bf16split(qv.w, qh.w, ql.w);
      bf16split(xv.x, xh.x, xl.x); bf16split(xv.y, xh.y, xl.y);
      bf16split(xv.z, xh.z, xl.z); bf16split(xv.w, xh.w, xl.w);
      *(ushort4*)(dq_h + 4*i) = qh; *(ushort4*)(dq_l + 4*i) = ql;
      *(ushort4*)(dx_h + 4*i) = xh; *(ushort4*)(dx_l + 4*i) = xl;
    }
  }
  __syncthreads();

  const f32x4 z = {0.f, 0.f, 0.f, 0.f};
  f32x4 accQ[2][4], accK[2][4];
#pragma unroll
  for (int a = 0; a < 2; ++a)
#pragma unroll
    for (int bt = 0; bt < 4; ++bt) { accQ[a][bt] = z; accK[a][bt] = z; }

#pragma unroll 2
  for (int kc = 0; kc < 8; ++kc) {
    s16x8 a0h[2], a0l[2], a1h[2], a1l[2];
#pragma unroll
    for (int a = 0; a < 2; ++a) {
      const int tile = wv * 2 + a;
      a0h[a] = *(const s16x8*)(wpk + (((size_t)(0 * 8 + kc) * 16 + tile) * 64 + l) * 8);
      a0l[a] = *(const s16x8*)(wpk + (((size_t)(1 * 8 + kc) * 16 + tile) * 64 + l) * 8);
      a1h[a] = *(const s16x8*)(wpk + (((size_t)(2 * 8 + kc) * 16 + tile) * 64 + l) * 8);
      a1l[a] = *(const s16x8*)(wpk + (((size_t)(3 * 8 + kc) * 16 + tile) * 64 + l) * 8);
    }
#pragma unroll
    for (int bt = 0; bt < 4; ++bt) {
      const int row  = bt * 16 + (l & 15);
      const int coff = kc * 32 + (l >> 4) * 8;
      const ushort* base = act + row * CSTR + coff;
      const s16x8 bqh = *(const s16x8*)(base + 0 * PXT * CSTR);
      const s16x8 bql = *(const s16x8*)(base + 1 * PXT * CSTR);
      const s16x8 bxh = *(const s16x8*)(base + 2 * PXT * CSTR);
      const s16x8 bxl = *(const s16x8*)(base + 3 * PXT * CSTR);
#pragma unroll
      for (int a = 0; a < 2; ++a) {
        accQ[a][bt] = __builtin_amdgcn_mfma_f32_16x16x32_bf16(a0h[a], bqh, accQ[a][bt], 0, 0, 0);
        accQ[a][bt] = __builtin_amdgcn_mfma_f32_16x16x32_bf16(a0h[a], bql, accQ[a][bt], 0, 0, 0);
        accQ[a][bt] = __builtin_amdgcn_mfma_f32_16x16x32_bf16(a0l[a], bqh, accQ[a][bt], 0, 0, 0);
        accK[a][bt] = __builtin_amdgcn_mfma_f32_16x16x32_bf16(a1h[a], bxh, accK[a][bt], 0, 0, 0);
        accK[a][bt] = __builtin_amdgcn_mfma_f32_16x16x32_bf16(a1h[a], bxl, accK[a][bt], 0, 0, 0);
        accK[a][bt] = __builtin_amdgcn_mfma_f32_16x16x32_bf16(a1l[a], bxh, accK[a][bt], 0, 0, 0);
      }
    }
  }

  // ---- epilogue: per-pixel stats (D layout: col=l&15 -> px, row=(l>>4)*4+r)
  float bq[2][4], bk[2][4];
#pragma unroll
  for (int a = 0; a < 2; ++a)
#pragma unroll
    for (int r = 0; r < 4; ++r) {
      const int o = wv * 32 + a * 16 + (l >> 4) * 4 + r;
      bq[a][r] = b0[o]; bk[a][r] = b1[o];
    }

  float st[4][5];
#pragma unroll
  for (int bt = 0; bt < 4; ++bt)
#pragma unroll
    for (int s = 0; s < 5; ++s) st[bt][s] = 0.f;
#pragma unroll
  for (int bt = 0; bt < 4; ++bt)
#pragma unroll
    for (int a = 0; a < 2; ++a)
#pragma unroll
      for (int r = 0; r < 4; ++r) {
        const float Qv = accQ[a][bt][r] + bq[a][r];
        const float Kv = accK[a][bt][r] + bk[a][r];
        st[bt][0] += Qv;
        st[bt][1] += Kv;
        st[bt][2] = fmaf(Qv, Qv, st[bt][2]);
        st[bt][3] = fmaf(Kv, Kv, st[bt][3]);
        st[bt][4] = fmaf(Qv, Kv, st[bt][4]);
      }
#pragma unroll
  for (int bt = 0; bt < 4; ++bt)
#pragma unroll
    for (int s = 0; s < 5; ++s) {
      float v = st[bt][s];
      v += __shfl_xor(v, 16, 64);
      v += __shfl_xor(v, 32, 64);
      st[bt][s] = v;
    }

  __syncthreads();                      // K-loop LDS reads done; alias stats
  float* sl = (float*)act;              // [8 waves][64 px][5]
  {
    const int mybt = l >> 4, col = l & 15;
#pragma unroll
    for (int s = 0; s < 5; ++s)
      sl[((wv * 64) + mybt * 16 + col) * 5 + s] = st[mybt][s];
  }
  __syncthreads();
  if (tid < PXT) {
    float sQ = 0.f, sK = 0.f, sQQ = 0.f, sKK = 0.f, sQK = 0.f;
#pragma unroll
    for (int w8 = 0; w8 < 8; ++w8) {
      const float* p = sl + ((w8 * 64) + tid) * 5;
      sQ += p[0]; sK += p[1]; sQQ += p[2]; sKK += p[3]; sQK += p[4];
    }
    const float num = sQK - sQ * sK * (1.f / 256.f);
    const float dq  = sQQ - sQ * sQ * (1.f / 256.f) + 1e-5f;
    const float dk  = sKK - sK * sK * (1.f / 256.f) + 1e-5f;
    out[(size_t)b * HW + px0 + tid] = num / sqrtf(dq * dk);
  }
}

// ---------------------------------------------------------------------------
// Fallback path (R1/R2 proven), used only if ws is too small.
// ---------------------------------------------------------------------------
__global__ __launch_bounds__(256) void transpose_k(
    const float* __restrict__ w0, const float* __restrict__ w1,
    float* __restrict__ w0T, float* __restrict__ w1T) {
  __shared__ float tile[32][33];
  const float* src = blockIdx.y ? w1 : w0;
  float*       dst = blockIdx.y ? w1T : w0T;
  const int bx = blockIdx.x & 7, by = blockIdx.x >> 3;
  const int tx = threadIdx.x & 31, ty = threadIdx.x >> 5;
#pragma unroll
  for (int i = 0; i < 32; i += 8)
    tile[ty + i][tx] = src[(by*32 + ty + i)*Cd + bx*32 + tx];
  __syncthreads();
#pragma unroll
  for (int i = 0; i < 32; i += 8)
    dst[(bx*32 + ty + i)*Cd + by*32 + tx] = tile[tx][ty + i];
}

__global__ __launch_bounds__(256) void deform_max_k(
    const float* __restrict__ x, const float* __restrict__ off,
    float* __restrict__ q) {
  const int b   = blockIdx.y;
  const int c0  = blockIdx.z << 5;
  const int hw0 = (blockIdx.x << 8) + threadIdx.x;
  const int h   = hw0 >> 7;
  const int w   = hw0 & (Wd - 1);
  const float* offb = off + ((size_t)b * 18) * HW + hw0;
  int   i00[9], i01[9], i10[9], i11[9];
  float c00[9], c01[9], c10[9], c11[9];
#pragma unroll
  for (int k = 0; k < 9; ++k) {
    const int kh = k / 3 - 1, kw = k % 3 - 1;
    const float oy = offb[(size_t)(2*k)   * HW];
    const float ox = offb[(size_t)(2*k+1) * HW];
    const float py = (float)(h + kh) + oy;
    const float px = (float)(w + kw) + ox;
    const float y0f = floorf(py), x0f = floorf(px);
    const float wy = py - y0f, wx = px - x0f;
    const int y0 = (int)y0f, x0 = (int)x0f;
    const int y1 = y0 + 1,  x1 = x0 + 1;
    const float vy0 = (y0 >= 0 && y0 < Hd) ? 1.f : 0.f;
    const float vy1 = (y1 >= 0 && y1 < Hd) ? 1.f : 0.f;
    const float vx0 = (x0 >= 0 && x0 < Wd) ? 1.f : 0.f;
    const float vx1 = (x1 >= 0 && x1 < Wd) ? 1.f : 0.f;
    const int cy0 = min(max(y0, 0), Hd-1), cy1 = min(max(y1, 0), Hd-1);
    const int cx0 = min(max(x0, 0), Wd-1), cx1 = min(max(x1, 0), Wd-1);
    i00[k] = cy0 * Wd + cx0;  i01[k] = cy0 * Wd + cx1;
    i10[k] = cy1 * Wd + cx0;  i11[k] = cy1 * Wd + cx1;
    c00[k] = (1.f-wy)*(1.f-wx) * vy0*vx0;
    c01[k] = (1.f-wy)*wx       * vy0*vx1;
    c10[k] = wy*(1.f-wx)       * vy1*vx0;
    c11[k] = wy*wx             * vy1*vx1;
  }
  const float* xb = x + ((size_t)(b * Cd + c0)) * HW;
  float*       qb = q + ((size_t)(b * Cd + c0)) * HW + hw0;
#pragma unroll 4
  for (int c = 0; c < 32; ++c) {
    const float* xc = xb + (size_t)c * HW;
    float m = -3.402823466e38f;
#pragma unroll
    for (int k = 0; k < 9; ++k) {
      const float s = c00[k]*xc[i00[k]] + c01[k]*xc[i01[k]]
                    + c10[k]*xc[i10[k]] + c11[k]*xc[i11[k]];
      m = fmaxf(m, s);
    }
    qb[(size_t)c * HW] = m;
  }
}

__global__ __launch_bounds__(512) void fused_k(
    const float* __restrict__ x, const float* __restrict__ q,
    const float* __restrict__ w0T, const float* __restrict__ w1T,
    const float* __restrict__ b0, const float* __restrict__ b1,
    float* __restrict__ out) {
  __shared__ float w0s[KC * 256];
  __shared__ float w1s[KC * 256];
  __shared__ float qs [KC * PX];
  __shared__ float xs [KC * PX];
  const int b    = blockIdx.y;
  const int px0  = blockIdx.x * PX;
  const int tid  = threadIdx.x;
  const int o_t  = tid & 31;
  const int px_t = tid >> 5;
  float accQ[8][8], accK[8][8];
#pragma unroll
  for (int i = 0; i < 8; ++i) {
    const int o = (i < 4) ? (4*o_t + i) : (128 + 4*o_t + (i - 4));
    const float bqv = b0[o], bkv = b1[o];
#pragma unroll
    for (int j = 0; j < 8; ++j) { accQ[i][j] = bqv; accK[i][j] = bkv; }
  }
  const float* qb = q + ((size_t)b * Cd) * HW + px0;
  const float* xb = x + ((size_t)b * Cd) * HW + px0;
  for (int kc = 0; kc < Cd; kc += KC) {
    __syncthreads();
    {
      const float4* s0 = (const float4*)(w0T + (size_t)kc * 256);
      const float4* s1 = (const float4*)(w1T + (size_t)kc * 256);
      float4* d0 = (float4*)w0s;
      float4* d1 = (float4*)w1s;
#pragma unroll
      for (int i = 0; i < 4; ++i) {
        d0[tid*4 + i] = s0[tid*4 + i];
        d1[tid*4 + i] = s1[tid*4 + i];
      }
#pragma unroll
      for (int i = 0; i < 2; ++i) {
        const int f  = tid*2 + i;
        const int cc = f >> 5, p4 = f & 31;
        ((float4*)qs)[cc*(PX/4) + p4] =
            ((const float4*)(qb + (size_t)(kc+cc) * HW))[p4];
        ((float4*)xs)[cc*(PX/4) + p4] =
            ((const float4*)(xb + (size_t)(kc+cc) * HW))[p4];
      }
    }
    __syncthreads();
#pragma unroll 4
    for (int cc = 0; cc < KC; ++cc) {
      float a0[8], a1[8], qv[8], xv[8];
      *(float4*)&a0[0] = *(const float4*)&w0s[cc*256 + 4*o_t];
      *(float4*)&a0[4] = *(const float4*)&w0s[cc*256 + 128 + 4*o_t];
      *(float4*)&a1[0] = *(const float4*)&w1s[cc*256 + 4*o_t];
      *(float4*)&a1[4] = *(const float4*)&w1s[cc*256 + 128 + 4*o_t];
      *(float4*)&qv[0] = *(const float4*)&qs[cc*PX + 8*px_t];
      *(float4*)&qv[4] = *(const float4*)&qs[cc*PX + 8*px_t + 4];
      *(float4*)&xv[0] = *(const float4*)&xs[cc*PX + 8*px_t];
      *(float4*)&xv[4] = *(const float4*)&xs[cc*PX + 8*px_t + 4];
#pragma unroll
      for (int i = 0; i < 8; ++i)
#pragma unroll
        for (int j = 0; j < 8; ++j) {
          accQ[i][j] = fmaf(a0[i], qv[j], accQ[i][j]);
          accK[i][j] = fmaf(a1[i], xv[j], accK[i][j]);
        }
    }
  }
  float outv[8];
#pragma unroll
  for (int j = 0; j < 8; ++j) {
    float sQ = 0.f, sK = 0.f, sQQ = 0.f, sKK = 0.f, sQK = 0.f;
#pragma unroll
    for (int i = 0; i < 8; ++i) {
      const float Qv = accQ[i][j], Kv = accK[i][j];
      sQ += Qv; sK += Kv;
      sQQ = fmaf(Qv, Qv, sQQ);
      sKK = fmaf(Kv, Kv, sKK);
      sQK = fmaf(Qv, Kv, sQK);
    }
#pragma unroll
    for (int m = 1; m < 32; m <<= 1) {
      sQ  += __shfl_xor(sQ,  m, 64);
      sK  += __shfl_xor(sK,  m, 64);
      sQQ += __shfl_xor(sQQ, m, 64);
      sKK += __shfl_xor(sKK, m, 64);
      sQK += __shfl_xor(sQK, m, 64);
    }
    const float num = sQK - sQ*sK*(1.f/256.f);
    const float dq  = sQQ - sQ*sQ*(1.f/256.f) + 1e-5f;
    const float dk  = sKK - sK*sK*(1.f/256.f) + 1e-5f;
    outv[j] = num / sqrtf(dq * dk);
  }
  if (o_t == 0) {
    float* ob = out + (size_t)b * HW + px0 + px_t*8;
#pragma unroll
    for (int j = 0; j < 8; ++j) ob[j] = outv[j];
  }
}

// ---------------------------------------------------------------------------
extern "C" void kernel_launch(void* const* d_in, const int* in_sizes, int n_in,
                              void* d_out, int out_size, void* d_ws, size_t ws_size,
                              hipStream_t stream) {
  const float* x   = (const float*)d_in[0];
  const float* off = (const float*)d_in[1];
  const float* w0  = (const float*)d_in[2];
  const float* b0  = (const float*)d_in[3];
  const float* w1  = (const float*)d_in[4];
  const float* b1  = (const float*)d_in[5];
  float* out = (float*)d_out;

  const size_t tensor_elems = (size_t)Bd * Cd * HW;       // 16.78M floats
  const size_t wpk_bytes    = 4 * 65536 * sizeof(ushort); // 512 KB
  const size_t need_fast    = wpk_bytes + 2 * tensor_elems * 4;

  if (ws_size >= need_fast) {
    ushort* wpk = (ushort*)d_ws;
    float*  xT  = (float*)((char*)d_ws + wpk_bytes);      // [B][HW][C]
    float*  qT  = xT + tensor_elems;                      // [B][HW][C]
    prep_w_k     <<<64, 256, 0, stream>>>(w0, w1, wpk);
    transpose_x_k<<<dim3(HW/32, Cd/32, Bd), 256, 0, stream>>>(x, xT);
    deform_coal_k<<<dim3(HW/(4*PPW), Bd), 256, 0, stream>>>(xT, off, qT);
    fused_mfma_k <<<dim3(HW/PXT, Bd), 512, 0, stream>>>(xT, qT, wpk, b0, b1, out);
  } else {
    float* w0T = (float*)d_ws;
    float* w1T = w0T + 65536;
    float* qws = w1T + 65536;
    transpose_k <<<dim3(64, 2),     256, 0, stream>>>(w0, w1, w0T, w1T);
    deform_max_k<<<dim3(64, Bd, 8), 256, 0, stream>>>(x, off, qws);
    fused_k     <<<dim3(HW/PX, Bd), 512, 0, stream>>>(x, qws, w0T, w1T, b0, b1, out);
  }
}

// Round 7
// 320.990 us; speedup vs baseline: 2.9182x; 1.1597x over previous
//
#include <hip/hip_runtime.h>
#include <math.h>
#include <float.h>

#define Bd 4
#define Cd 256
#define Hd 128
#define Wd 128
#define HW (Hd*Wd)

#define PX 128   // pixels per block in fallback fused kernel
#define KC 32
#define PPW 8    // pixels per wave in deform_coal_k

#define PXT 64   // pixels per block in MFMA fused kernel
#define CSTR 264 // padded LDS row stride (bf16 elems); 528 B -> conflict-free b128

typedef __attribute__((ext_vector_type(8))) short s16x8;
typedef __attribute__((ext_vector_type(4))) float f32x4;

// rne float -> bf16 hi, and bf16(residual) lo
__device__ __forceinline__ void bf16split(float v, ushort& h, ushort& lo_) {
  uint u = __builtin_bit_cast(uint, v);
  uint uh = u + 0x7FFFu + ((u >> 16) & 1u);
  ushort hh = (ushort)(uh >> 16);
  float hf = __builtin_bit_cast(float, (uint)hh << 16);
  float res = v - hf;                       // exact
  uint r = __builtin_bit_cast(uint, res);
  uint rl = r + 0x7FFFu + ((r >> 16) & 1u);
  h = hh; lo_ = (ushort)(rl >> 16);
}

// ---------------------------------------------------------------------------
// prep_w_k: pack w0,w1 ([O][C] fp32) into MFMA-A-fragment order, hi/lo bf16.
// ---------------------------------------------------------------------------
__global__ __launch_bounds__(256) void prep_w_k(
    const float* __restrict__ w0, const float* __restrict__ w1,
    ushort* __restrict__ wpk) {
  const int t    = blockIdx.x * 256 + threadIdx.x;  // 0..16383
  const int lane = t & 63;
  const int tile = (t >> 6) & 15;
  const int kc   = (t >> 10) & 7;
  const int mat  = t >> 13;
  const float* wsrc = mat ? w1 : w0;
  const int o  = tile * 16 + (lane & 15);
  const int c0 = kc * 32 + (lane >> 4) * 8;
  ushort hi[8], lo[8];
#pragma unroll
  for (int j = 0; j < 8; ++j)
    bf16split(wsrc[o * Cd + c0 + j], hi[j], lo[j]);
  const size_t bh = ((((size_t)(mat * 2 + 0) * 8 + kc) * 16 + tile) * 64 + lane) * 8;
  const size_t bl = ((((size_t)(mat * 2 + 1) * 8 + kc) * 16 + tile) * 64 + lane) * 8;
#pragma unroll
  for (int j = 0; j < 8; ++j) { wpk[bh + j] = hi[j]; wpk[bl + j] = lo[j]; }
}

// ---------------------------------------------------------------------------
// transpose_x_k: x [B][C][HW] -> xT [B][HW][C] (fp32), for coalesced gathers.
// ---------------------------------------------------------------------------
__global__ __launch_bounds__(256) void transpose_x_k(
    const float* __restrict__ x, float* __restrict__ xT) {
  __shared__ float t[32][33];
  const int b   = blockIdx.z;
  const int hw0 = blockIdx.x * 32;
  const int c0  = blockIdx.y * 32;
  const int tx = threadIdx.x & 31, ty = threadIdx.x >> 5;
  const float* xb  = x  + (size_t)b * Cd * HW;
  float*       xTb = xT + (size_t)b * HW * Cd;
#pragma unroll
  for (int i = 0; i < 32; i += 8)
    t[ty + i][tx] = xb[(size_t)(c0 + ty + i) * HW + hw0 + tx];
  __syncthreads();
#pragma unroll
  for (int i = 0; i < 32; i += 8)
    xTb[(size_t)(hw0 + ty + i) * Cd + c0 + tx] = t[tx][ty + i];
}

// ---------------------------------------------------------------------------
// deform_coal_k (R4): deformable 3x3 unfold + max, channel-coalesced.
// R4 changes vs R3:
//  (1) XCD-chunked block swizzle: each XCD works a contiguous image band
//      (~8 MB) instead of the whole 16 MB image -> better L2 hit rate.
//  (2) Lane-parallel coeff computation: the wave's 72 (pixel,tap) bilinear
//      coeff jobs run across lanes in one pass, stored to LDS; the channel
//      gather loop reads them back as wave-uniform broadcasts. Kills the
//      64x-replicated coeff math and the per-pixel serial dependency.
// ---------------------------------------------------------------------------
__device__ __forceinline__ void deform_job(
    int j, int pbase, const float* __restrict__ offb, uint* __restrict__ dstbase) {
  const int px = j / 9, k = j - px * 9;
  const int p = pbase + px;
  const int h = p >> 7, w = p & (Wd - 1);
  const float oy = offb[(2 * k) * HW + p];
  const float ox = offb[(2 * k + 1) * HW + p];
  const float py = (float)(h + k / 3 - 1) + oy;
  const float pxx = (float)(w + k % 3 - 1) + ox;
  const float y0f = floorf(py), x0f = floorf(pxx);
  const float wy = py - y0f, wx = pxx - x0f;
  const int y0 = (int)y0f, x0 = (int)x0f;
  const int y1 = y0 + 1,  x1 = x0 + 1;
  const float vy0 = (y0 >= 0 && y0 < Hd) ? 1.f : 0.f;
  const float vy1 = (y1 >= 0 && y1 < Hd) ? 1.f : 0.f;
  const float vx0 = (x0 >= 0 && x0 < Wd) ? 1.f : 0.f;
  const float vx1 = (x1 >= 0 && x1 < Wd) ? 1.f : 0.f;
  const int cy0 = min(max(y0, 0), Hd-1), cy1 = min(max(y1, 0), Hd-1);
  const int cx0 = min(max(x0, 0), Wd-1), cx1 = min(max(x1, 0), Wd-1);
  uint4 iv;
  iv.x = (uint)(cy0 * Wd + cx0) * Cd;
  iv.y = (uint)(cy0 * Wd + cx1) * Cd;
  iv.z = (uint)(cy1 * Wd + cx0) * Cd;
  iv.w = (uint)(cy1 * Wd + cx1) * Cd;
  float4 cv;
  cv.x = (1.f-wy)*(1.f-wx) * vy0*vx0;
  cv.y = (1.f-wy)*wx       * vy0*vx1;
  cv.z = wy*(1.f-wx)       * vy1*vx0;
  cv.w = wy*wx             * vy1*vx1;
  uint* d = dstbase + (size_t)(px * 9 + k) * 8;
  *(uint4*)d = iv;
  *(float4*)(d + 4) = cv;
}

__global__ __launch_bounds__(256) void deform_coal_k(
    const float* __restrict__ xT, const float* __restrict__ off,
    float* __restrict__ qT) {
  __shared__ __align__(16) uint coef[4][PPW * 9 * 8];   // 9216 B

  // XCD-chunked swizzle over the flattened 2048-block grid (2048 % 8 == 0).
  const int bid = blockIdx.x;
  const int swz = (bid & 7) * 256 + (bid >> 3);
  const int b    = swz >> 9;          // 512 blocks per batch
  const int tile = swz & 511;

  const int wv    = threadIdx.x >> 6;
  const int lane  = threadIdx.x & 63;
  const int pbase = (tile * 4 + wv) * PPW;

  const float* offb = off + (size_t)b * 18 * HW;

  // ---- job phase: 72 (px,tap) jobs across 64 lanes (8 lanes take a 2nd job)
  deform_job(lane, pbase, offb, &coef[wv][0]);
  if (lane < 8) deform_job(64 + lane, pbase, offb, &coef[wv][0]);
  __syncthreads();

  const float* xTb = xT + (size_t)b * HW * Cd + lane * 4;
  float*       qTb = qT + (size_t)b * HW * Cd + lane * 4;

#pragma unroll 2
  for (int pi = 0; pi < PPW; ++pi) {
    const int p = pbase + pi;
    float m0 = -FLT_MAX, m1 = -FLT_MAX, m2 = -FLT_MAX, m3 = -FLT_MAX;
#pragma unroll
    for (int k = 0; k < 9; ++k) {
      const uint* cp = &coef[wv][(pi * 9 + k) * 8];
      const uint4  iv = *(const uint4*)cp;          // wave-uniform broadcast
      const float4 cw = *(const float4*)(cp + 4);
      const float4 v00 = *(const float4*)(xTb + iv.x);
      const float4 v01 = *(const float4*)(xTb + iv.y);
      const float4 v10 = *(const float4*)(xTb + iv.z);
      const float4 v11 = *(const float4*)(xTb + iv.w);
      m0 = fmaxf(m0, fmaf(cw.x, v00.x, fmaf(cw.y, v01.x, fmaf(cw.z, v10.x, cw.w*v11.x))));
      m1 = fmaxf(m1, fmaf(cw.x, v00.y, fmaf(cw.y, v01.y, fmaf(cw.z, v10.y, cw.w*v11.y))));
      m2 = fmaxf(m2, fmaf(cw.x, v00.z, fmaf(cw.y, v01.z, fmaf(cw.z, v10.z, cw.w*v11.z))));
      m3 = fmaxf(m3, fmaf(cw.x, v00.w, fmaf(cw.y, v01.w, fmaf(cw.z, v10.w, cw.w*v11.w))));
    }
    float4 r; r.x = m0; r.y = m1; r.z = m2; r.w = m3;
    *(float4*)(qTb + (size_t)p * Cd) = r;
  }
}

// ---------------------------------------------------------------------------
// fused_mfma_k: Q = W0*q + b0, K = W1*x + b1 via split-bf16 MFMA
// (3 passes: AhBh + AhBl + AlBh), channel-norm cosine epilogue.
// ---------------------------------------------------------------------------
__global__ __launch_bounds__(512) void fused_mfma_k(
    const float* __restrict__ xT, const float* __restrict__ qT,
    const ushort* __restrict__ wpk,
    const float* __restrict__ b0, const float* __restrict__ b1,
    float* __restrict__ out) {
  __shared__ ushort act[4 * PXT * CSTR];   // qh | ql | xh | xl = 135168 B
  const int b   = blockIdx.y;
  const int px0 = blockIdx.x * PXT;
  const int tid = threadIdx.x;
  const int l   = tid & 63, wv = tid >> 6;

  // ---- stage activations: fp32 -> hi/lo bf16 in LDS
  {
    const int r  = tid >> 3;          // 0..63
    const int c0 = (tid & 7) * 32;    // 0..224
    const float* qrow = qT + ((size_t)b * HW + px0 + r) * Cd + c0;
    const float* xrow = xT + ((size_t)b * HW + px0 + r) * Cd + c0;
    ushort* dq_h = act + 0 * PXT * CSTR + r * CSTR + c0;
    ushort* dq_l = act + 1 * PXT * CSTR + r * CSTR + c0;
    ushort* dx_h = act + 2 * PXT * CSTR + r * CSTR + c0;
    ushort* dx_l = act + 3 * PXT * CSTR + r * CSTR + c0;
#pragma unroll
    for (int i = 0; i < 8; ++i) {
      const float4 qv = ((const float4*)qrow)[i];
      const float4 xv = ((const float4*)xrow)[i];
      ushort4 qh, ql, xh, xl;
      bf16split(qv.x, qh.x, ql.x); bf16split(qv.y, qh.y, ql.y);
      bf16split(qv.z, qh.z, ql.z); bf16split(qv.w, qh.w, ql.w);
      bf16split(xv.x, xh.x, xl.x); bf16split(xv.y, xh.y, xl.y);
      bf16split(xv.z, xh.z, xl.z); bf16split(xv.w, xh.w, xl.w);
      *(ushort4*)(dq_h + 4*i) = qh; *(ushort4*)(dq_l + 4*i) = ql;
      *(ushort4*)(dx_h + 4*i) = xh; *(ushort4*)(dx_l + 4*i) = xl;
    }
  }
  __syncthreads();

  const f32x4 z = {0.f, 0.f, 0.f, 0.f};
  f32x4 accQ[2][4], accK[2][4];
#pragma unroll
  for (int a = 0; a < 2; ++a)
#pragma unroll
    for (int bt = 0; bt < 4; ++bt) { accQ[a][bt] = z; accK[a][bt] = z; }

#pragma unroll 2
  for (int kc = 0; kc < 8; ++kc) {
    s16x8 a0h[2], a0l[2], a1h[2], a1l[2];
#pragma unroll
    for (int a = 0; a < 2; ++a) {
      const int tile = wv * 2 + a;
      a0h[a] = *(const s16x8*)(wpk + (((size_t)(0 * 8 + kc) * 16 + tile) * 64 + l) * 8);
      a0l[a] = *(const s16x8*)(wpk + (((size_t)(1 * 8 + kc) * 16 + tile) * 64 + l) * 8);
      a1h[a] = *(const s16x8*)(wpk + (((size_t)(2 * 8 + kc) * 16 + tile) * 64 + l) * 8);
      a1l[a] = *(const s16x8*)(wpk + (((size_t)(3 * 8 + kc) * 16 + tile) * 64 + l) * 8);
    }
#pragma unroll
    for (int bt = 0; bt < 4; ++bt) {
      const int row  = bt * 16 + (l & 15);
      const int coff = kc * 32 + (l >> 4) * 8;
      const ushort* base = act + row * CSTR + coff;
      const s16x8 bqh = *(const s16x8*)(base + 0 * PXT * CSTR);
      const s16x8 bql = *(const s16x8*)(base + 1 * PXT * CSTR);
      const s16x8 bxh = *(const s16x8*)(base + 2 * PXT * CSTR);
      const s16x8 bxl = *(const s16x8*)(base + 3 * PXT * CSTR);
#pragma unroll
      for (int a = 0; a < 2; ++a) {
        accQ[a][bt] = __builtin_amdgcn_mfma_f32_16x16x32_bf16(a0h[a], bqh, accQ[a][bt], 0, 0, 0);
        accQ[a][bt] = __builtin_amdgcn_mfma_f32_16x16x32_bf16(a0h[a], bql, accQ[a][bt], 0, 0, 0);
        accQ[a][bt] = __builtin_amdgcn_mfma_f32_16x16x32_bf16(a0l[a], bqh, accQ[a][bt], 0, 0, 0);
        accK[a][bt] = __builtin_amdgcn_mfma_f32_16x16x32_bf16(a1h[a], bxh, accK[a][bt], 0, 0, 0);
        accK[a][bt] = __builtin_amdgcn_mfma_f32_16x16x32_bf16(a1h[a], bxl, accK[a][bt], 0, 0, 0);
        accK[a][bt] = __builtin_amdgcn_mfma_f32_16x16x32_bf16(a1l[a], bxh, accK[a][bt], 0, 0, 0);
      }
    }
  }

  // ---- epilogue: per-pixel stats (D layout: col=l&15 -> px, row=(l>>4)*4+r)
  float bq[2][4], bk[2][4];
#pragma unroll
  for (int a = 0; a < 2; ++a)
#pragma unroll
    for (int r = 0; r < 4; ++r) {
      const int o = wv * 32 + a * 16 + (l >> 4) * 4 + r;
      bq[a][r] = b0[o]; bk[a][r] = b1[o];
    }

  float st[4][5];
#pragma unroll
  for (int bt = 0; bt < 4; ++bt)
#pragma unroll
    for (int s = 0; s < 5; ++s) st[bt][s] = 0.f;
#pragma unroll
  for (int bt = 0; bt < 4; ++bt)
#pragma unroll
    for (int a = 0; a < 2; ++a)
#pragma unroll
      for (int r = 0; r < 4; ++r) {
        const float Qv = accQ[a][bt][r] + bq[a][r];
        const float Kv = accK[a][bt][r] + bk[a][r];
        st[bt][0] += Qv;
        st[bt][1] += Kv;
        st[bt][2] = fmaf(Qv, Qv, st[bt][2]);
        st[bt][3] = fmaf(Kv, Kv, st[bt][3]);
        st[bt][4] = fmaf(Qv, Kv, st[bt][4]);
      }
#pragma unroll
  for (int bt = 0; bt < 4; ++bt)
#pragma unroll
    for (int s = 0; s < 5; ++s) {
      float v = st[bt][s];
      v += __shfl_xor(v, 16, 64);
      v += __shfl_xor(v, 32, 64);
      st[bt][s] = v;
    }

  __syncthreads();                      // K-loop LDS reads done; alias stats
  float* sl = (float*)act;              // [8 waves][64 px][5]
  {
    const int mybt = l >> 4, col = l & 15;
#pragma unroll
    for (int s = 0; s < 5; ++s)
      sl[((wv * 64) + mybt * 16 + col) * 5 + s] = st[mybt][s];
  }
  __syncthreads();
  if (tid < PXT) {
    float sQ = 0.f, sK = 0.f, sQQ = 0.f, sKK = 0.f, sQK = 0.f;
#pragma unroll
    for (int w8 = 0; w8 < 8; ++w8) {
      const float* p = sl + ((w8 * 64) + tid) * 5;
      sQ += p[0]; sK += p[1]; sQQ += p[2]; sKK += p[3]; sQK += p[4];
    }
    const float num = sQK - sQ * sK * (1.f / 256.f);
    const float dq  = sQQ - sQ * sQ * (1.f / 256.f) + 1e-5f;
    const float dk  = sKK - sK * sK * (1.f / 256.f) + 1e-5f;
    out[(size_t)b * HW + px0 + tid] = num / sqrtf(dq * dk);
  }
}

// ---------------------------------------------------------------------------
// Fallback path (R1/R2 proven), used only if ws is too small.
// ---------------------------------------------------------------------------
__global__ __launch_bounds__(256) void transpose_k(
    const float* __restrict__ w0, const float* __restrict__ w1,
    float* __restrict__ w0T, float* __restrict__ w1T) {
  __shared__ float tile[32][33];
  const float* src = blockIdx.y ? w1 : w0;
  float*       dst = blockIdx.y ? w1T : w0T;
  const int bx = blockIdx.x & 7, by = blockIdx.x >> 3;
  const int tx = threadIdx.x & 31, ty = threadIdx.x >> 5;
#pragma unroll
  for (int i = 0; i < 32; i += 8)
    tile[ty + i][tx] = src[(by*32 + ty + i)*Cd + bx*32 + tx];
  __syncthreads();
#pragma unroll
  for (int i = 0; i < 32; i += 8)
    dst[(bx*32 + ty + i)*Cd + by*32 + tx] = tile[tx][ty + i];
}

__global__ __launch_bounds__(256) void deform_max_k(
    const float* __restrict__ x, const float* __restrict__ off,
    float* __restrict__ q) {
  const int b   = blockIdx.y;
  const int c0  = blockIdx.z << 5;
  const int hw0 = (blockIdx.x << 8) + threadIdx.x;
  const int h   = hw0 >> 7;
  const int w   = hw0 & (Wd - 1);
  const float* offb = off + ((size_t)b * 18) * HW + hw0;
  int   i00[9], i01[9], i10[9], i11[9];
  float c00[9], c01[9], c10[9], c11[9];
#pragma unroll
  for (int k = 0; k < 9; ++k) {
    const int kh = k / 3 - 1, kw = k % 3 - 1;
    const float oy = offb[(size_t)(2*k)   * HW];
    const float ox = offb[(size_t)(2*k+1) * HW];
    const float py = (float)(h + kh) + oy;
    const float px = (float)(w + kw) + ox;
    const float y0f = floorf(py), x0f = floorf(px);
    const float wy = py - y0f, wx = px - x0f;
    const int y0 = (int)y0f, x0 = (int)x0f;
    const int y1 = y0 + 1,  x1 = x0 + 1;
    const float vy0 = (y0 >= 0 && y0 < Hd) ? 1.f : 0.f;
    const float vy1 = (y1 >= 0 && y1 < Hd) ? 1.f : 0.f;
    const float vx0 = (x0 >= 0 && x0 < Wd) ? 1.f : 0.f;
    const float vx1 = (x1 >= 0 && x1 < Wd) ? 1.f : 0.f;
    const int cy0 = min(max(y0, 0), Hd-1), cy1 = min(max(y1, 0), Hd-1);
    const int cx0 = min(max(x0, 0), Wd-1), cx1 = min(max(x1, 0), Wd-1);
    i00[k] = cy0 * Wd + cx0;  i01[k] = cy0 * Wd + cx1;
    i10[k] = cy1 * Wd + cx0;  i11[k] = cy1 * Wd + cx1;
    c00[k] = (1.f-wy)*(1.f-wx) * vy0*vx0;
    c01[k] = (1.f-wy)*wx       * vy0*vx1;
    c10[k] = wy*(1.f-wx)       * vy1*vx0;
    c11[k] = wy*wx             * vy1*vx1;
  }
  const float* xb = x + ((size_t)(b * Cd + c0)) * HW;
  float*       qb = q + ((size_t)(b * Cd + c0)) * HW + hw0;
#pragma unroll 4
  for (int c = 0; c < 32; ++c) {
    const float* xc = xb + (size_t)c * HW;
    float m = -3.402823466e38f;
#pragma unroll
    for (int k = 0; k < 9; ++k) {
      const float s = c00[k]*xc[i00[k]] + c01[k]*xc[i01[k]]
                    + c10[k]*xc[i10[k]] + c11[k]*xc[i11[k]];
      m = fmaxf(m, s);
    }
    qb[(size_t)c * HW] = m;
  }
}

__global__ __launch_bounds__(512) void fused_k(
    const float* __restrict__ x, const float* __restrict__ q,
    const float* __restrict__ w0T, const float* __restrict__ w1T,
    const float* __restrict__ b0, const float* __restrict__ b1,
    float* __restrict__ out) {
  __shared__ float w0s[KC * 256];
  __shared__ float w1s[KC * 256];
  __shared__ float qs [KC * PX];
  __shared__ float xs [KC * PX];
  const int b    = blockIdx.y;
  const int px0  = blockIdx.x * PX;
  const int tid  = threadIdx.x;
  const int o_t  = tid & 31;
  const int px_t = tid >> 5;
  float accQ[8][8], accK[8][8];
#pragma unroll
  for (int i = 0; i < 8; ++i) {
    const int o = (i < 4) ? (4*o_t + i) : (128 + 4*o_t + (i - 4));
    const float bqv = b0[o], bkv = b1[o];
#pragma unroll
    for (int j = 0; j < 8; ++j) { accQ[i][j] = bqv; accK[i][j] = bkv; }
  }
  const float* qb = q + ((size_t)b * Cd) * HW + px0;
  const float* xb = x + ((size_t)b * Cd) * HW + px0;
  for (int kc = 0; kc < Cd; kc += KC) {
    __syncthreads();
    {
      const float4* s0 = (const float4*)(w0T + (size_t)kc * 256);
      const float4* s1 = (const float4*)(w1T + (size_t)kc * 256);
      float4* d0 = (float4*)w0s;
      float4* d1 = (float4*)w1s;
#pragma unroll
      for (int i = 0; i < 4; ++i) {
        d0[tid*4 + i] = s0[tid*4 + i];
        d1[tid*4 + i] = s1[tid*4 + i];
      }
#pragma unroll
      for (int i = 0; i < 2; ++i) {
        const int f  = tid*2 + i;
        const int cc = f >> 5, p4 = f & 31;
        ((float4*)qs)[cc*(PX/4) + p4] =
            ((const float4*)(qb + (size_t)(kc+cc) * HW))[p4];
        ((float4*)xs)[cc*(PX/4) + p4] =
            ((const float4*)(xb + (size_t)(kc+cc) * HW))[p4];
      }
    }
    __syncthreads();
#pragma unroll 4
    for (int cc = 0; cc < KC; ++cc) {
      float a0[8], a1[8], qv[8], xv[8];
      *(float4*)&a0[0] = *(const float4*)&w0s[cc*256 + 4*o_t];
      *(float4*)&a0[4] = *(const float4*)&w0s[cc*256 + 128 + 4*o_t];
      *(float4*)&a1[0] = *(const float4*)&w1s[cc*256 + 4*o_t];
      *(float4*)&a1[4] = *(const float4*)&w1s[cc*256 + 128 + 4*o_t];
      *(float4*)&qv[0] = *(const float4*)&qs[cc*PX + 8*px_t];
      *(float4*)&qv[4] = *(const float4*)&qs[cc*PX + 8*px_t + 4];
      *(float4*)&xv[0] = *(const float4*)&xs[cc*PX + 8*px_t];
      *(float4*)&xv[4] = *(const float4*)&xs[cc*PX + 8*px_t + 4];
#pragma unroll
      for (int i = 0; i < 8; ++i)
#pragma unroll
        for (int j = 0; j < 8; ++j) {
          accQ[i][j] = fmaf(a0[i], qv[j], accQ[i][j]);
          accK[i][j] = fmaf(a1[i], xv[j], accK[i][j]);
        }
    }
  }
  float outv[8];
#pragma unroll
  for (int j = 0; j < 8; ++j) {
    float sQ = 0.f, sK = 0.f, sQQ = 0.f, sKK = 0.f, sQK = 0.f;
#pragma unroll
    for (int i = 0; i < 8; ++i) {
      const float Qv = accQ[i][j], Kv = accK[i][j];
      sQ += Qv; sK += Kv;
      sQQ = fmaf(Qv, Qv, sQQ);
      sKK = fmaf(Kv, Kv, sKK);
      sQK = fmaf(Qv, Kv, sQK);
    }
#pragma unroll
    for (int m = 1; m < 32; m <<= 1) {
      sQ  += __shfl_xor(sQ,  m, 64);
      sK  += __shfl_xor(sK,  m, 64);
      sQQ += __shfl_xor(sQQ, m, 64);
      sKK += __shfl_xor(sKK, m, 64);
      sQK += __shfl_xor(sQK, m, 64);
    }
    const float num = sQK - sQ*sK*(1.f/256.f);
    const float dq  = sQQ - sQ*sQ*(1.f/256.f) + 1e-5f;
    const float dk  = sKK - sK*sK*(1.f/256.f) + 1e-5f;
    outv[j] = num / sqrtf(dq * dk);
  }
  if (o_t == 0) {
    float* ob = out + (size_t)b * HW + px0 + px_t*8;
#pragma unroll
    for (int j = 0; j < 8; ++j) ob[j] = outv[j];
  }
}

// ---------------------------------------------------------------------------
extern "C" void kernel_launch(void* const* d_in, const int* in_sizes, int n_in,
                              void* d_out, int out_size, void* d_ws, size_t ws_size,
                              hipStream_t stream) {
  const float* x   = (const float*)d_in[0];
  const float* off = (const float*)d_in[1];
  const float* w0  = (const float*)d_in[2];
  const float* b0  = (const float*)d_in[3];
  const float* w1  = (const float*)d_in[4];
  const float* b1  = (const float*)d_in[5];
  float* out = (float*)d_out;

  const size_t tensor_elems = (size_t)Bd * Cd * HW;       // 16.78M floats
  const size_t wpk_bytes    = 4 * 65536 * sizeof(ushort); // 512 KB
  const size_t need_fast    = wpk_bytes + 2 * tensor_elems * 4;

  if (ws_size >= need_fast) {
    ushort* wpk = (ushort*)d_ws;
    float*  xT  = (float*)((char*)d_ws + wpk_bytes);      // [B][HW][C]
    float*  qT  = xT + tensor_elems;                      // [B][HW][C]
    prep_w_k     <<<64, 256, 0, stream>>>(w0, w1, wpk);
    transpose_x_k<<<dim3(HW/32, Cd/32, Bd), 256, 0, stream>>>(x, xT);
    deform_coal_k<<<2048, 256, 0, stream>>>(xT, off, qT);
    fused_mfma_k <<<dim3(HW/PXT, Bd), 512, 0, stream>>>(xT, qT, wpk, b0, b1, out);
  } else {
    float* w0T = (float*)d_ws;
    float* w1T = w0T + 65536;
    float* qws = w1T + 65536;
    transpose_k <<<dim3(64, 2),     256, 0, stream>>>(w0, w1, w0T, w1T);
    deform_max_k<<<dim3(64, Bd, 8), 256, 0, stream>>>(x, off, qws);
    fused_k     <<<dim3(HW/PX, Bd), 512, 0, stream>>>(x, qws, w0T, w1T, b0, b1, out);
  }
}

// Round 8
// 281.483 us; speedup vs baseline: 3.3277x; 1.1404x over previous
//
#include <hip/hip_runtime.h>
#include <math.h>
#include <float.h>

#define Bd 4
#define Cd 256
#define Hd 128
#define Wd 128
#define HW (Hd*Wd)

#define PX 128   // pixels per block in fallback fused kernel
#define KC 32
#define PXM 32   // pixels per block in merged kernel
#define CSTR 264 // padded LDS row stride (bf16 elems); 528 B -> 2-way max on b128

typedef __attribute__((ext_vector_type(8))) short s16x8;
typedef __attribute__((ext_vector_type(4))) float f32x4;

// rne float -> bf16 hi, and bf16(residual) lo
__device__ __forceinline__ void bf16split(float v, ushort& h, ushort& lo_) {
  uint u = __builtin_bit_cast(uint, v);
  uint uh = u + 0x7FFFu + ((u >> 16) & 1u);
  ushort hh = (ushort)(uh >> 16);
  float hf = __builtin_bit_cast(float, (uint)hh << 16);
  float res = v - hf;                       // exact
  uint r = __builtin_bit_cast(uint, res);
  uint rl = r + 0x7FFFu + ((r >> 16) & 1u);
  h = hh; lo_ = (ushort)(rl >> 16);
}

// ---------------------------------------------------------------------------
// prep_w_k: pack w0,w1 ([O][C] fp32) into MFMA-A-fragment order, hi/lo bf16.
// wpk[((mat*2+part)*8 + kc)*16 + tile][lane][8]:
//   elem j = W[tile*16 + (lane&15)][kc*32 + (lane>>4)*8 + j]
// ---------------------------------------------------------------------------
__global__ __launch_bounds__(256) void prep_w_k(
    const float* __restrict__ w0, const float* __restrict__ w1,
    ushort* __restrict__ wpk) {
  const int t    = blockIdx.x * 256 + threadIdx.x;  // 0..16383
  const int lane = t & 63;
  const int tile = (t >> 6) & 15;
  const int kc   = (t >> 10) & 7;
  const int mat  = t >> 13;
  const float* wsrc = mat ? w1 : w0;
  const int o  = tile * 16 + (lane & 15);
  const int c0 = kc * 32 + (lane >> 4) * 8;
  ushort hi[8], lo[8];
#pragma unroll
  for (int j = 0; j < 8; ++j)
    bf16split(wsrc[o * Cd + c0 + j], hi[j], lo[j]);
  const size_t bh = ((((size_t)(mat * 2 + 0) * 8 + kc) * 16 + tile) * 64 + lane) * 8;
  const size_t bl = ((((size_t)(mat * 2 + 1) * 8 + kc) * 16 + tile) * 64 + lane) * 8;
#pragma unroll
  for (int j = 0; j < 8; ++j) { wpk[bh + j] = hi[j]; wpk[bl + j] = lo[j]; }
}

// ---------------------------------------------------------------------------
// transpose_x_k: x [B][C][HW] -> xT [B][HW][C] (fp32), for coalesced gathers.
// ---------------------------------------------------------------------------
__global__ __launch_bounds__(256) void transpose_x_k(
    const float* __restrict__ x, float* __restrict__ xT) {
  __shared__ float t[32][33];
  const int b   = blockIdx.z;
  const int hw0 = blockIdx.x * 32;
  const int c0  = blockIdx.y * 32;
  const int tx = threadIdx.x & 31, ty = threadIdx.x >> 5;
  const float* xb  = x  + (size_t)b * Cd * HW;
  float*       xTb = xT + (size_t)b * HW * Cd;
#pragma unroll
  for (int i = 0; i < 32; i += 8)
    t[ty + i][tx] = xb[(size_t)(c0 + ty + i) * HW + hw0 + tx];
  __syncthreads();
#pragma unroll
  for (int i = 0; i < 32; i += 8)
    xTb[(size_t)(hw0 + ty + i) * Cd + c0 + tx] = t[tx][ty + i];
}

// ---------------------------------------------------------------------------
// deform_job: one (pixel,tap) bilinear coeff job -> 4 indices + 4 weights.
// ---------------------------------------------------------------------------
__device__ __forceinline__ void deform_job(
    int j, int pbase, const float* __restrict__ offb, uint* __restrict__ dstbase) {
  const int px = j / 9, k = j - px * 9;
  const int p = pbase + px;
  const int h = p >> 7, w = p & (Wd - 1);
  const float oy = offb[(2 * k) * HW + p];
  const float ox = offb[(2 * k + 1) * HW + p];
  const float py = (float)(h + k / 3 - 1) + oy;
  const float pxx = (float)(w + k % 3 - 1) + ox;
  const float y0f = floorf(py), x0f = floorf(pxx);
  const float wy = py - y0f, wx = pxx - x0f;
  const int y0 = (int)y0f, x0 = (int)x0f;
  const int y1 = y0 + 1,  x1 = x0 + 1;
  const float vy0 = (y0 >= 0 && y0 < Hd) ? 1.f : 0.f;
  const float vy1 = (y1 >= 0 && y1 < Hd) ? 1.f : 0.f;
  const float vx0 = (x0 >= 0 && x0 < Wd) ? 1.f : 0.f;
  const float vx1 = (x1 >= 0 && x1 < Wd) ? 1.f : 0.f;
  const int cy0 = min(max(y0, 0), Hd-1), cy1 = min(max(y1, 0), Hd-1);
  const int cx0 = min(max(x0, 0), Wd-1), cx1 = min(max(x1, 0), Wd-1);
  uint4 iv;
  iv.x = (uint)(cy0 * Wd + cx0) * Cd;
  iv.y = (uint)(cy0 * Wd + cx1) * Cd;
  iv.z = (uint)(cy1 * Wd + cx0) * Cd;
  iv.w = (uint)(cy1 * Wd + cx1) * Cd;
  float4 cv;
  cv.x = (1.f-wy)*(1.f-wx) * vy0*vx0;
  cv.y = (1.f-wy)*wx       * vy0*vx1;
  cv.z = wy*(1.f-wx)       * vy1*vx0;
  cv.w = wy*wx             * vy1*vx1;
  uint* d = dstbase + (size_t)(px * 9 + k) * 8;
  *(uint4*)d = iv;
  *(float4*)(d + 4) = cv;
}

// ---------------------------------------------------------------------------
// merged_k (R7): deform gather+max FUSED with the split-bf16 MFMA GEMMs +
// channel-norm cosine epilogue. Eliminates the 128 MB qT HBM round-trip and
// overlaps gather latency with GEMM of the co-resident block (2 blocks/CU).
// Block = 256 thr (4 waves), tile = 32 px x 256 outs.
//  A: lane-parallel bilinear coeffs (72 jobs/wave) -> coef LDS
//  B: gather+max (lane owns 4 ch), bf16split -> act q-rows directly
//  C: stage x rows fp32->hi/lo bf16 -> act x-rows
//  D: K-loop: A-frags from L2-resident wpk; B-frags from act; 6 MFMA/tile
//  E: per-pixel stats, shfl + cross-wave LDS reduce, cosine, store.
// ---------------------------------------------------------------------------
__global__ __launch_bounds__(256) void merged_k(
    const float* __restrict__ xT, const float* __restrict__ off,
    const ushort* __restrict__ wpk,
    const float* __restrict__ b0, const float* __restrict__ b1,
    float* __restrict__ out) {
  __shared__ ushort act[4 * PXM * CSTR];            // qh|ql|xh|xl = 67584 B
  __shared__ __align__(16) uint coef[4][8 * 9 * 8]; // 9216 B  (tot 76.8 KB -> 2 blk/CU)

  // XCD-chunked swizzle over 2048 blocks (2048 % 8 == 0 -> bijective).
  const int bid = blockIdx.x;
  const int swz = (bid & 7) * 256 + (bid >> 3);
  const int b    = swz >> 9;            // 512 blocks per batch
  const int tile = swz & 511;

  const int tid = threadIdx.x;
  const int l   = tid & 63, wv = tid >> 6;
  const int px0   = tile * PXM;         // block's 32 pixels
  const int pbase = px0 + wv * 8;       // wave's 8 pixels

  const float* offb = off + (size_t)b * 18 * HW;

  // ---- Phase A: coeffs (72 jobs across 64 lanes)
  deform_job(l, pbase, offb, &coef[wv][0]);
  if (l < 8) deform_job(64 + l, pbase, offb, &coef[wv][0]);
  __syncthreads();

  // ---- Phase B: gather + max + bf16split -> act q rows
  {
    const float* xTb = xT + (size_t)b * HW * Cd + l * 4;
    ushort* qh_base = act + 0 * PXM * CSTR;
    ushort* ql_base = act + 1 * PXM * CSTR;
#pragma unroll 2
    for (int pi = 0; pi < 8; ++pi) {
      float m0 = -FLT_MAX, m1 = -FLT_MAX, m2 = -FLT_MAX, m3 = -FLT_MAX;
#pragma unroll
      for (int k = 0; k < 9; ++k) {
        const uint* cp = &coef[wv][(pi * 9 + k) * 8];
        const uint4  iv = *(const uint4*)cp;        // wave-uniform broadcast
        const float4 cw = *(const float4*)(cp + 4);
        const float4 v00 = *(const float4*)(xTb + iv.x);
        const float4 v01 = *(const float4*)(xTb + iv.y);
        const float4 v10 = *(const float4*)(xTb + iv.z);
        const float4 v11 = *(const float4*)(xTb + iv.w);
        m0 = fmaxf(m0, fmaf(cw.x, v00.x, fmaf(cw.y, v01.x, fmaf(cw.z, v10.x, cw.w*v11.x))));
        m1 = fmaxf(m1, fmaf(cw.x, v00.y, fmaf(cw.y, v01.y, fmaf(cw.z, v10.y, cw.w*v11.y))));
        m2 = fmaxf(m2, fmaf(cw.x, v00.z, fmaf(cw.y, v01.z, fmaf(cw.z, v10.z, cw.w*v11.z))));
        m3 = fmaxf(m3, fmaf(cw.x, v00.w, fmaf(cw.y, v01.w, fmaf(cw.z, v10.w, cw.w*v11.w))));
      }
      ushort4 hh, ll;
      bf16split(m0, hh.x, ll.x); bf16split(m1, hh.y, ll.y);
      bf16split(m2, hh.z, ll.z); bf16split(m3, hh.w, ll.w);
      const int pl = wv * 8 + pi;                   // local pixel row 0..31
      *(ushort4*)(qh_base + pl * CSTR + l * 4) = hh;
      *(ushort4*)(ql_base + pl * CSTR + l * 4) = ll;
    }
  }

  // ---- Phase C: stage x rows fp32 -> hi/lo bf16
  {
    const int r  = tid >> 3;          // 0..31
    const int c0 = (tid & 7) * 32;    // 0..224
    const float* xrow = xT + ((size_t)b * HW + px0 + r) * Cd + c0;
    ushort* dx_h = act + 2 * PXM * CSTR + r * CSTR + c0;
    ushort* dx_l = act + 3 * PXM * CSTR + r * CSTR + c0;
#pragma unroll
    for (int i = 0; i < 8; ++i) {
      const float4 xv = ((const float4*)xrow)[i];
      ushort4 xh, xl;
      bf16split(xv.x, xh.x, xl.x); bf16split(xv.y, xh.y, xl.y);
      bf16split(xv.z, xh.z, xl.z); bf16split(xv.w, xh.w, xl.w);
      *(ushort4*)(dx_h + 4*i) = xh; *(ushort4*)(dx_l + 4*i) = xl;
    }
  }
  __syncthreads();

  // ---- Phase D: K-loop (no barriers)
  const f32x4 z = {0.f, 0.f, 0.f, 0.f};
  f32x4 accQ[4][2], accK[4][2];
#pragma unroll
  for (int a = 0; a < 4; ++a)
#pragma unroll
    for (int bt = 0; bt < 2; ++bt) { accQ[a][bt] = z; accK[a][bt] = z; }

#pragma unroll 2
  for (int kc = 0; kc < 8; ++kc) {
    s16x8 a0h[4], a0l[4], a1h[4], a1l[4];
#pragma unroll
    for (int a = 0; a < 4; ++a) {
      const int ta = wv * 4 + a;      // 16 o-tiles / 4 waves
      a0h[a] = *(const s16x8*)(wpk + (((size_t)(0 * 8 + kc) * 16 + ta) * 64 + l) * 8);
      a0l[a] = *(const s16x8*)(wpk + (((size_t)(1 * 8 + kc) * 16 + ta) * 64 + l) * 8);
      a1h[a] = *(const s16x8*)(wpk + (((size_t)(2 * 8 + kc) * 16 + ta) * 64 + l) * 8);
      a1l[a] = *(const s16x8*)(wpk + (((size_t)(3 * 8 + kc) * 16 + ta) * 64 + l) * 8);
    }
#pragma unroll
    for (int bt = 0; bt < 2; ++bt) {
      const int row  = bt * 16 + (l & 15);
      const int coff = kc * 32 + (l >> 4) * 8;
      const ushort* base = act + row * CSTR + coff;
      const s16x8 bqh = *(const s16x8*)(base + 0 * PXM * CSTR);
      const s16x8 bql = *(const s16x8*)(base + 1 * PXM * CSTR);
      const s16x8 bxh = *(const s16x8*)(base + 2 * PXM * CSTR);
      const s16x8 bxl = *(const s16x8*)(base + 3 * PXM * CSTR);
#pragma unroll
      for (int a = 0; a < 4; ++a) {
        accQ[a][bt] = __builtin_amdgcn_mfma_f32_16x16x32_bf16(a0h[a], bqh, accQ[a][bt], 0, 0, 0);
        accQ[a][bt] = __builtin_amdgcn_mfma_f32_16x16x32_bf16(a0h[a], bql, accQ[a][bt], 0, 0, 0);
        accQ[a][bt] = __builtin_amdgcn_mfma_f32_16x16x32_bf16(a0l[a], bqh, accQ[a][bt], 0, 0, 0);
        accK[a][bt] = __builtin_amdgcn_mfma_f32_16x16x32_bf16(a1h[a], bxh, accK[a][bt], 0, 0, 0);
        accK[a][bt] = __builtin_amdgcn_mfma_f32_16x16x32_bf16(a1h[a], bxl, accK[a][bt], 0, 0, 0);
        accK[a][bt] = __builtin_amdgcn_mfma_f32_16x16x32_bf16(a1l[a], bxh, accK[a][bt], 0, 0, 0);
      }
    }
  }

  // ---- Phase E: epilogue.  D layout: col=l&15 -> pixel bt*16+(l&15),
  // row o = wv*64 + a*16 + (l>>4)*4 + r.
  float bq[4][4], bk[4][4];
#pragma unroll
  for (int a = 0; a < 4; ++a)
#pragma unroll
    for (int r = 0; r < 4; ++r) {
      const int o = wv * 64 + a * 16 + (l >> 4) * 4 + r;
      bq[a][r] = b0[o]; bk[a][r] = b1[o];
    }

  float st[2][5];
#pragma unroll
  for (int bt = 0; bt < 2; ++bt)
#pragma unroll
    for (int s = 0; s < 5; ++s) st[bt][s] = 0.f;
#pragma unroll
  for (int bt = 0; bt < 2; ++bt)
#pragma unroll
    for (int a = 0; a < 4; ++a)
#pragma unroll
      for (int r = 0; r < 4; ++r) {
        const float Qv = accQ[a][bt][r] + bq[a][r];
        const float Kv = accK[a][bt][r] + bk[a][r];
        st[bt][0] += Qv;
        st[bt][1] += Kv;
        st[bt][2] = fmaf(Qv, Qv, st[bt][2]);
        st[bt][3] = fmaf(Kv, Kv, st[bt][3]);
        st[bt][4] = fmaf(Qv, Kv, st[bt][4]);
      }
#pragma unroll
  for (int bt = 0; bt < 2; ++bt)
#pragma unroll
    for (int s = 0; s < 5; ++s) {
      float v = st[bt][s];
      v += __shfl_xor(v, 16, 64);
      v += __shfl_xor(v, 32, 64);      // now = wave's 64-out sums for pixel bt*16+(l&15)
      st[bt][s] = v;
    }

  __syncthreads();                      // act reads done; alias stats buffer
  float* sl = (float*)act;              // [4 waves][32 px][5]
  if (l < 32) {
    const int mybt = l >> 4, col = l & 15;
#pragma unroll
    for (int s = 0; s < 5; ++s)
      sl[((wv * 32) + mybt * 16 + col) * 5 + s] = st[mybt][s];
  }
  __syncthreads();
  if (tid < PXM) {
    float sQ = 0.f, sK = 0.f, sQQ = 0.f, sKK = 0.f, sQK = 0.f;
#pragma unroll
    for (int w4 = 0; w4 < 4; ++w4) {
      const float* p = sl + ((w4 * 32) + tid) * 5;
      sQ += p[0]; sK += p[1]; sQQ += p[2]; sKK += p[3]; sQK += p[4];
    }
    const float num = sQK - sQ * sK * (1.f / 256.f);
    const float dq  = sQQ - sQ * sQ * (1.f / 256.f) + 1e-5f;
    const float dk  = sKK - sK * sK * (1.f / 256.f) + 1e-5f;
    out[(size_t)b * HW + px0 + tid] = num / sqrtf(dq * dk);
  }
}

// ---------------------------------------------------------------------------
// Fallback path (R1/R2 proven), used only if ws is too small.
// ---------------------------------------------------------------------------
__global__ __launch_bounds__(256) void transpose_k(
    const float* __restrict__ w0, const float* __restrict__ w1,
    float* __restrict__ w0T, float* __restrict__ w1T) {
  __shared__ float tile[32][33];
  const float* src = blockIdx.y ? w1 : w0;
  float*       dst = blockIdx.y ? w1T : w0T;
  const int bx = blockIdx.x & 7, by = blockIdx.x >> 3;
  const int tx = threadIdx.x & 31, ty = threadIdx.x >> 5;
#pragma unroll
  for (int i = 0; i < 32; i += 8)
    tile[ty + i][tx] = src[(by*32 + ty + i)*Cd + bx*32 + tx];
  __syncthreads();
#pragma unroll
  for (int i = 0; i < 32; i += 8)
    dst[(bx*32 + ty + i)*Cd + by*32 + tx] = tile[tx][ty + i];
}

__global__ __launch_bounds__(256) void deform_max_k(
    const float* __restrict__ x, const float* __restrict__ off,
    float* __restrict__ q) {
  const int b   = blockIdx.y;
  const int c0  = blockIdx.z << 5;
  const int hw0 = (blockIdx.x << 8) + threadIdx.x;
  const int h   = hw0 >> 7;
  const int w   = hw0 & (Wd - 1);
  const float* offb = off + ((size_t)b * 18) * HW + hw0;
  int   i00[9], i01[9], i10[9], i11[9];
  float c00[9], c01[9], c10[9], c11[9];
#pragma unroll
  for (int k = 0; k < 9; ++k) {
    const int kh = k / 3 - 1, kw = k % 3 - 1;
    const float oy = offb[(size_t)(2*k)   * HW];
    const float ox = offb[(size_t)(2*k+1) * HW];
    const float py = (float)(h + kh) + oy;
    const float px = (float)(w + kw) + ox;
    const float y0f = floorf(py), x0f = floorf(px);
    const float wy = py - y0f, wx = px - x0f;
    const int y0 = (int)y0f, x0 = (int)x0f;
    const int y1 = y0 + 1,  x1 = x0 + 1;
    const float vy0 = (y0 >= 0 && y0 < Hd) ? 1.f : 0.f;
    const float vy1 = (y1 >= 0 && y1 < Hd) ? 1.f : 0.f;
    const float vx0 = (x0 >= 0 && x0 < Wd) ? 1.f : 0.f;
    const float vx1 = (x1 >= 0 && x1 < Wd) ? 1.f : 0.f;
    const int cy0 = min(max(y0, 0), Hd-1), cy1 = min(max(y1, 0), Hd-1);
    const int cx0 = min(max(x0, 0), Wd-1), cx1 = min(max(x1, 0), Wd-1);
    i00[k] = cy0 * Wd + cx0;  i01[k] = cy0 * Wd + cx1;
    i10[k] = cy1 * Wd + cx0;  i11[k] = cy1 * Wd + cx1;
    c00[k] = (1.f-wy)*(1.f-wx) * vy0*vx0;
    c01[k] = (1.f-wy)*wx       * vy0*vx1;
    c10[k] = wy*(1.f-wx)       * vy1*vx0;
    c11[k] = wy*wx             * vy1*vx1;
  }
  const float* xb = x + ((size_t)(b * Cd + c0)) * HW;
  float*       qb = q + ((size_t)(b * Cd + c0)) * HW + hw0;
#pragma unroll 4
  for (int c = 0; c < 32; ++c) {
    const float* xc = xb + (size_t)c * HW;
    float m = -3.402823466e38f;
#pragma unroll
    for (int k = 0; k < 9; ++k) {
      const float s = c00[k]*xc[i00[k]] + c01[k]*xc[i01[k]]
                    + c10[k]*xc[i10[k]] + c11[k]*xc[i11[k]];
      m = fmaxf(m, s);
    }
    qb[(size_t)c * HW] = m;
  }
}

__global__ __launch_bounds__(512) void fused_k(
    const float* __restrict__ x, const float* __restrict__ q,
    const float* __restrict__ w0T, const float* __restrict__ w1T,
    const float* __restrict__ b0, const float* __restrict__ b1,
    float* __restrict__ out) {
  __shared__ float w0s[KC * 256];
  __shared__ float w1s[KC * 256];
  __shared__ float qs [KC * PX];
  __shared__ float xs [KC * PX];
  const int b    = blockIdx.y;
  const int px0  = blockIdx.x * PX;
  const int tid  = threadIdx.x;
  const int o_t  = tid & 31;
  const int px_t = tid >> 5;
  float accQ[8][8], accK[8][8];
#pragma unroll
  for (int i = 0; i < 8; ++i) {
    const int o = (i < 4) ? (4*o_t + i) : (128 + 4*o_t + (i - 4));
    const float bqv = b0[o], bkv = b1[o];
#pragma unroll
    for (int j = 0; j < 8; ++j) { accQ[i][j] = bqv; accK[i][j] = bkv; }
  }
  const float* qb = q + ((size_t)b * Cd) * HW + px0;
  const float* xb = x + ((size_t)b * Cd) * HW + px0;
  for (int kc = 0; kc < Cd; kc += KC) {
    __syncthreads();
    {
      const float4* s0 = (const float4*)(w0T + (size_t)kc * 256);
      const float4* s1 = (const float4*)(w1T + (size_t)kc * 256);
      float4* d0 = (float4*)w0s;
      float4* d1 = (float4*)w1s;
#pragma unroll
      for (int i = 0; i < 4; ++i) {
        d0[tid*4 + i] = s0[tid*4 + i];
        d1[tid*4 + i] = s1[tid*4 + i];
      }
#pragma unroll
      for (int i = 0; i < 2; ++i) {
        const int f  = tid*2 + i;
        const int cc = f >> 5, p4 = f & 31;
        ((float4*)qs)[cc*(PX/4) + p4] =
            ((const float4*)(qb + (size_t)(kc+cc) * HW))[p4];
        ((float4*)xs)[cc*(PX/4) + p4] =
            ((const float4*)(xb + (size_t)(kc+cc) * HW))[p4];
      }
    }
    __syncthreads();
#pragma unroll 4
    for (int cc = 0; cc < KC; ++cc) {
      float a0[8], a1[8], qv[8], xv[8];
      *(float4*)&a0[0] = *(const float4*)&w0s[cc*256 + 4*o_t];
      *(float4*)&a0[4] = *(const float4*)&w0s[cc*256 + 128 + 4*o_t];
      *(float4*)&a1[0] = *(const float4*)&w1s[cc*256 + 4*o_t];
      *(float4*)&a1[4] = *(const float4*)&w1s[cc*256 + 128 + 4*o_t];
      *(float4*)&qv[0] = *(const float4*)&qs[cc*PX + 8*px_t];
      *(float4*)&qv[4] = *(const float4*)&qs[cc*PX + 8*px_t + 4];
      *(float4*)&xv[0] = *(const float4*)&xs[cc*PX + 8*px_t];
      *(float4*)&xv[4] = *(const float4*)&xs[cc*PX + 8*px_t + 4];
#pragma unroll
      for (int i = 0; i < 8; ++i)
#pragma unroll
        for (int j = 0; j < 8; ++j) {
          accQ[i][j] = fmaf(a0[i], qv[j], accQ[i][j]);
          accK[i][j] = fmaf(a1[i], xv[j], accK[i][j]);
        }
    }
  }
  float outv[8];
#pragma unroll
  for (int j = 0; j < 8; ++j) {
    float sQ = 0.f, sK = 0.f, sQQ = 0.f, sKK = 0.f, sQK = 0.f;
#pragma unroll
    for (int i = 0; i < 8; ++i) {
      const float Qv = accQ[i][j], Kv = accK[i][j];
      sQ += Qv; sK += Kv;
      sQQ = fmaf(Qv, Qv, sQQ);
      sKK = fmaf(Kv, Kv, sKK);
      sQK = fmaf(Qv, Kv, sQK);
    }
#pragma unroll
    for (int m = 1; m < 32; m <<= 1) {
      sQ  += __shfl_xor(sQ,  m, 64);
      sK  += __shfl_xor(sK,  m, 64);
      sQQ += __shfl_xor(sQQ, m, 64);
      sKK += __shfl_xor(sKK, m, 64);
      sQK += __shfl_xor(sQK, m, 64);
    }
    const float num = sQK - sQ*sK*(1.f/256.f);
    const float dq  = sQQ - sQ*sQ*(1.f/256.f) + 1e-5f;
    const float dk  = sKK - sK*sK*(1.f/256.f) + 1e-5f;
    outv[j] = num / sqrtf(dq * dk);
  }
  if (o_t == 0) {
    float* ob = out + (size_t)b * HW + px0 + px_t*8;
#pragma unroll
    for (int j = 0; j < 8; ++j) ob[j] = outv[j];
  }
}

// ---------------------------------------------------------------------------
extern "C" void kernel_launch(void* const* d_in, const int* in_sizes, int n_in,
                              void* d_out, int out_size, void* d_ws, size_t ws_size,
                              hipStream_t stream) {
  const float* x   = (const float*)d_in[0];
  const float* off = (const float*)d_in[1];
  const float* w0  = (const float*)d_in[2];
  const float* b0  = (const float*)d_in[3];
  const float* w1  = (const float*)d_in[4];
  const float* b1  = (const float*)d_in[5];
  float* out = (float*)d_out;

  const size_t tensor_elems = (size_t)Bd * Cd * HW;       // 16.78M floats
  const size_t wpk_bytes    = 4 * 65536 * sizeof(ushort); // 512 KB
  const size_t need_fast    = wpk_bytes + tensor_elems * 4;

  if (ws_size >= need_fast) {
    ushort* wpk = (ushort*)d_ws;
    float*  xT  = (float*)((char*)d_ws + wpk_bytes);      // [B][HW][C], 64 MiB
    prep_w_k     <<<64, 256, 0, stream>>>(w0, w1, wpk);
    transpose_x_k<<<dim3(HW/32, Cd/32, Bd), 256, 0, stream>>>(x, xT);
    merged_k     <<<2048, 256, 0, stream>>>(xT, off, wpk, b0, b1, out);
  } else {
    float* w0T = (float*)d_ws;
    float* w1T = w0T + 65536;
    float* qws = w1T + 65536;
    transpose_k <<<dim3(64, 2),     256, 0, stream>>>(w0, w1, w0T, w1T);
    deform_max_k<<<dim3(64, Bd, 8), 256, 0, stream>>>(x, off, qws);
    fused_k     <<<dim3(HW/PX, Bd), 512, 0, stream>>>(x, qws, w0T, w1T, b0, b1, out);
  }
}